// Round 12
// baseline (171.093 us; speedup 1.0000x reference)
//
#include <hip/hip_runtime.h>

#define DIM 768
#define NTOK 4096
#define HID 3072

typedef __attribute__((ext_vector_type(8))) short bf16x8;
typedef __attribute__((ext_vector_type(4))) float f32x4;

__device__ inline unsigned short f2bf(float f){
  unsigned u = __float_as_uint(f);
  u += 0x7fff + ((u >> 16) & 1);
  return (unsigned short)(u >> 16);
}
__device__ inline unsigned cvt_pk_bf16(float a, float b){
  unsigned r;
  asm("v_cvt_pk_bf16_f32 %0, %1, %2" : "=v"(r) : "v"(a), "v"(b));
  return r;
}
__device__ inline void gload_lds16(const void* g, void* l){
  __builtin_amdgcn_global_load_lds(
      (const __attribute__((address_space(1))) unsigned int*)g,
      (__attribute__((address_space(3))) unsigned int*)l, 16, 0, 0);
}
template<int N> __device__ inline void wait_vmcnt(){
  if constexpr (N == 0) asm volatile("s_waitcnt vmcnt(0)" ::: "memory");
  else if constexpr (N == 4) asm volatile("s_waitcnt vmcnt(4)" ::: "memory");
  else if constexpr (N == 8) asm volatile("s_waitcnt vmcnt(8)" ::: "memory");
  else static_assert(N == 0, "unsupported vmcnt");
}
// 64B-row tiles: chunk-level XOR (2-way classes on fragment reads)
__device__ inline int swz_read(int row, int hi){
  return (row * 64 + hi * 16) ^ ((row & 7) << 4);
}

// ---------------- LayerNorm: fp32 in -> bf16 out, 1 wave per 768-row ----------------
__global__ __launch_bounds__(256) void ln_kernel(const float* __restrict__ x,
    const float* __restrict__ g, const float* __restrict__ b,
    unsigned short* __restrict__ out)
{
  int row = blockIdx.x * 4 + (threadIdx.x >> 6);
  int lane = threadIdx.x & 63;
  const float* xr = x + (size_t)row * DIM;
  float4 v[3];
  float s = 0.f, s2 = 0.f;
#pragma unroll
  for (int j = 0; j < 3; ++j){
    v[j] = *(const float4*)(xr + j * 256 + lane * 4);
    s  += v[j].x + v[j].y + v[j].z + v[j].w;
    s2 += v[j].x*v[j].x + v[j].y*v[j].y + v[j].z*v[j].z + v[j].w*v[j].w;
  }
#pragma unroll
  for (int m = 1; m < 64; m <<= 1){ s += __shfl_xor(s, m, 64); s2 += __shfl_xor(s2, m, 64); }
  float mu  = s * (1.f / 768.f);
  float var = s2 * (1.f / 768.f) - mu * mu;
  float inv = rsqrtf(var + 1e-5f);
#pragma unroll
  for (int j = 0; j < 3; ++j){
    int c0 = j * 256 + lane * 4;
    float vv[4] = { v[j].x, v[j].y, v[j].z, v[j].w };
    ushort4 o4;
    o4.x = f2bf((vv[0] - mu) * inv * g[c0 + 0] + b[c0 + 0]);
    o4.y = f2bf((vv[1] - mu) * inv * g[c0 + 1] + b[c0 + 1]);
    o4.z = f2bf((vv[2] - mu) * inv * g[c0 + 2] + b[c0 + 2]);
    o4.w = f2bf((vv[3] - mu) * inv * g[c0 + 3] + b[c0 + 3]);
    *(ushort4*)(out + (size_t)row * DIM + c0) = o4;
  }
}

// ------- fused weight transposes: 4 weights, W[K][N] fp32 -> Wt[N][K] bf16 ----------
__global__ __launch_bounds__(256) void transpose4_kernel(
    const float* __restrict__ w_qkv, const float* __restrict__ w_proj,
    const float* __restrict__ w_fc1, const float* __restrict__ w_fc2,
    unsigned short* __restrict__ tq, unsigned short* __restrict__ tp,
    unsigned short* __restrict__ t1, unsigned short* __restrict__ t2)
{
  __shared__ __align__(16) unsigned short tile[32][33];
  int id = blockIdx.x;
  const float* W; unsigned short* Wt; int K, N, tx_n;
  if (id < 1728)      { W = w_qkv;  Wt = tq; K = 768;  N = 2304; tx_n = 72; }
  else if (id < 2304) { W = w_proj; Wt = tp; K = 768;  N = 768;  tx_n = 24; id -= 1728; }
  else if (id < 4608) { W = w_fc1;  Wt = t1; K = 768;  N = 3072; tx_n = 96; id -= 2304; }
  else                { W = w_fc2;  Wt = t2; K = 3072; N = 768;  tx_n = 24; id -= 4608; }
  int n0 = (id % tx_n) * 32, k0 = (id / tx_n) * 32;
  int tx = threadIdx.x & 31, ty = threadIdx.x >> 5;
#pragma unroll
  for (int i = 0; i < 32; i += 8)
    tile[ty + i][tx] = f2bf(W[(size_t)(k0 + ty + i) * N + n0 + tx]);
  __syncthreads();
#pragma unroll
  for (int i = 0; i < 32; i += 8)
    Wt[(size_t)(n0 + ty + i) * K + k0 + tx] = tile[tx][ty + i];
}

// ---------------- pack attention mask into bit-words: pm[b][kt] bit k = mask!=0 ------
__global__ __launch_bounds__(256) void pack_mask_kernel(const int* __restrict__ am,
    unsigned long long* __restrict__ pm)
{
  int lane = threadIdx.x & 63, w = threadIdx.x >> 6, b = blockIdx.x;
  for (int k = w; k < 16; k += 4){
    unsigned long long m = __ballot(am[b * 1024 + k * 64 + lane] != 0);
    if (lane == 0) pm[b * 16 + k] = m;
  }
}

// ------- QKV GEMM: 256 thr, BM=128 x BN=96, rotated 3-buffer, split epilogue --------
// grid (2304/96=24, 32) = 768 blocks = exactly 3/CU balanced.
__global__ __launch_bounds__(256) void gemm_qkv_kernel(
    const unsigned short* __restrict__ A,   // [M][768] bf16
    const unsigned short* __restrict__ Bt,  // [2304][768] bf16
    const float* __restrict__ bias,         // [2304]
    unsigned short* __restrict__ q_out,
    unsigned short* __restrict__ k_out,
    unsigned short* __restrict__ v_out,
    int M, int N, int K)
{
  constexpr int BM = 128, BN = 96, BK = 32, DEPTH = 3;
  constexpr int MI = 4, NI = 3;              // wave tile 64x48, wave grid 2x2
  constexpr int SMEM_B = DEPTH * (BM + BN) * BK * 2;   // 43008 B
  __shared__ __align__(16) char smem[SMEM_B];
  auto As = (unsigned short(*)[BM * BK])smem;
  auto Bs = (unsigned short(*)[BN * BK])(smem + DEPTH * BM * BK * 2);
  const int t = threadIdx.x, lane = t & 63, wid = t >> 6;
  const int lo = lane & 15, hi = lane >> 4;
  const int wr = wid >> 1, wc = wid & 1;

  const int gx = gridDim.x;
  const int nwg = gx * gridDim.y;
  const int lin = blockIdx.y * gx + blockIdx.x;
  const int swz = (lin & 7) * (nwg >> 3) + (lin >> 3);
  const int bm = (swz / gx) * BM, bn = (swz % gx) * BN;

  // hoisted staging sources; chunk map: c<512 -> A chunk c; else B chunk (wrap >=384)
  const unsigned short *p0, *p1, *p2, *p3;
  int d3;
  {
    int c, rp, r, q;
    c = t;       rp = c >> 2; r = rp ^ ((rp >> 2) & 1); q = (c & 3) ^ (r & 3);
    p0 = A  + (size_t)(bm + r) * K + q * 8;
    c = 256 + t; rp = c >> 2; r = rp ^ ((rp >> 2) & 1); q = (c & 3) ^ (r & 3);
    p1 = A  + (size_t)(bm + r) * K + q * 8;
    c = t;       rp = c >> 2; r = rp ^ ((rp >> 2) & 1); q = (c & 3) ^ (r & 3);
    p2 = Bt + (size_t)(bn + r) * K + q * 8;
    int c2w = (t < 128) ? 256 + t : t - 128;           // benign duplicate for t>=128
    c = c2w;     rp = c >> 2; r = rp ^ ((rp >> 2) & 1); q = (c & 3) ^ (r & 3);
    p3 = Bt + (size_t)(bn + r) * K + q * 8;
    d3 = c2w * 8;
  }
  int ofsA[MI], ofsB[NI];
#pragma unroll
  for (int i = 0; i < MI; ++i) ofsA[i] = swz_read(wr * 64 + i * 16 + lo, hi);
#pragma unroll
  for (int j = 0; j < NI; ++j) ofsB[j] = swz_read(wc * 48 + j * 16 + lo, hi);

  f32x4 acc[MI][NI];
#pragma unroll
  for (int i = 0; i < MI; ++i)
#pragma unroll
    for (int j = 0; j < NI; ++j) acc[i][j] = (f32x4){0.f, 0.f, 0.f, 0.f};

  const int NIT = K / BK;                    // 24, % 3 == 0
  auto stagefull = [&](int buf) __attribute__((always_inline)) {
    gload_lds16(p0, &As[buf][t * 8]);
    gload_lds16(p1, &As[buf][(256 + t) * 8]);
    gload_lds16(p2, &Bs[buf][t * 8]);
    gload_lds16(p3, &Bs[buf][d3]);
    p0 += BK; p1 += BK; p2 += BK; p3 += BK;
  };
  auto kbody = [&](int it, int RB, int WB) __attribute__((always_inline)) {
    if (it < NIT - 1) wait_vmcnt<4>(); else wait_vmcnt<0>();
    __builtin_amdgcn_sched_barrier(0);
    __builtin_amdgcn_s_barrier();
    __builtin_amdgcn_sched_barrier(0);
    if (it + 2 < NIT) stagefull(WB);
    const char* as = (const char*)As[RB];
    const char* bs = (const char*)Bs[RB];
    bf16x8 af[MI], bfr[NI];
#pragma unroll
    for (int i = 0; i < MI; ++i) af[i]  = *(const bf16x8*)(as + ofsA[i]);
#pragma unroll
    for (int j = 0; j < NI; ++j) bfr[j] = *(const bf16x8*)(bs + ofsB[j]);
#pragma unroll
    for (int i = 0; i < MI; ++i)
#pragma unroll
      for (int j = 0; j < NI; ++j)
        acc[i][j] = __builtin_amdgcn_mfma_f32_16x16x32_bf16(af[i], bfr[j], acc[i][j], 0, 0, 0);
  };

  stagefull(0);
  stagefull(1);
  for (int it = 0; it < NIT; it += 3){
    kbody(it,     0, 2);
    kbody(it + 1, 1, 0);
    kbody(it + 2, 2, 1);
  }

  __syncthreads();   // staging reads done; smem reusable

  // ---- split epilogue. acc: col=lane&15, row=(lane>>4)*4+r ----
  const int part = bn / 768;                 // 0=Q 1=K 2=V (uniform; 768 % 96 == 0)
  const int cloc = bn % 768;
  const int bb = bm >> 10, n0b = bm & 1023;
  unsigned short* ET = (unsigned short*)smem;
  if (part < 2){
    constexpr int LDE = 104;                 // 128 x 104 bf16 = 26.6KB
#pragma unroll
    for (int i = 0; i < MI; ++i)
#pragma unroll
      for (int j = 0; j < NI; ++j){
        int col_l = wc * 48 + j * 16 + lo;
        float bcol = bias[bn + col_l];
#pragma unroll
        for (int r = 0; r < 4; ++r)
          ET[(wr * 64 + i * 16 + hi * 4 + r) * LDE + col_l] = f2bf(acc[i][j][r] + bcol);
      }
    __syncthreads();
    unsigned short* dst0 = (part == 0) ? q_out : k_out;
#pragma unroll
    for (int p = 0; p < 8; ++p){
      int row = p * 16 + (t >> 4), chunk = t & 15;
      if (chunk < 12){
        int col = cloc + chunk * 8, hh = col >> 6, d0 = col & 63;
        *(bf16x8*)&dst0[((size_t)(bb * 12 + hh)) * 65536 + (n0b + row) * 64 + d0] =
            *(const bf16x8*)&ET[row * LDE + chunk * 8];
      }
    }
  } else {
    constexpr int LDV = 136;                 // 96 x 136 bf16 = 26.1KB, col-major store
#pragma unroll
    for (int i = 0; i < MI; ++i)
#pragma unroll
      for (int j = 0; j < NI; ++j){
        int col_l = wc * 48 + j * 16 + lo;
        float bcol = bias[bn + col_l];
#pragma unroll
        for (int r = 0; r < 4; ++r)
          ET[col_l * LDV + wr * 64 + i * 16 + hi * 4 + r] = f2bf(acc[i][j][r] + bcol);
      }
    __syncthreads();
#pragma unroll
    for (int p = 0; p < 6; ++p){
      int colg = p * 16 + (t >> 4), chunk = t & 15;
      int col = cloc + colg, hh = col >> 6, d = col & 63;
      *(bf16x8*)&v_out[((size_t)(bb * 12 + hh)) * 65536 + (size_t)d * 1024 + n0b + chunk * 8] =
          *(const bf16x8*)&ET[colg * LDV + chunk * 8];
    }
  }
}

// ------- N%96 GEMM: K-split-in-block, 512 thr, BM=128 x BN=96 -----------------------
// EPI: 1 = bias+GELU -> bf16 (FC1); 2 = bias+resid -> fp32 (proj, FC2)
template<int EPI>
__global__ __launch_bounds__(512) void gemm_ks_kernel(
    const unsigned short* __restrict__ A,   // [M][K] bf16
    const unsigned short* __restrict__ Bt,  // [N][K] bf16
    const float* __restrict__ bias,         // [N]
    const float* __restrict__ resid,        // [M][N] (EPI==2)
    void* __restrict__ Cout,                // [M][N] fp32 (EPI2) / bf16 (EPI1)
    int M, int N, int K)
{
  constexpr int BM = 128, BN = 96, BK = 64, DEPTH = 3;
  constexpr int MI = 4, NI = 3;
  constexpr int ACH = BM * BK / 8;         // 1024
  constexpr int BCH = BN * BK / 8;         // 768
  constexpr int NC = 4;
  constexpr int TILE_A = BM * BK * 2, TILE_B = BN * BK * 2;
  constexpr int LDE = BN + 4;              // 100 floats
  constexpr int SMEM_B = (DEPTH * (TILE_A + TILE_B) > BM * LDE * 4)
                       ?  DEPTH * (TILE_A + TILE_B) : BM * LDE * 4;   // 84KB
  __shared__ __align__(16) char smem[SMEM_B];
  auto As = (unsigned short(*)[BM * BK])smem;
  auto Bs = (unsigned short(*)[BN * BK])(smem + DEPTH * TILE_A);
  const int t = threadIdx.x, lane = t & 63, wid = t >> 6;
  const int lo = lane & 15, hi = lane >> 4;
  const int ks = wid & 1, wc = (wid >> 1) & 1, wr = wid >> 2;

  const int gx = gridDim.x;
  const int nwg = gx * gridDim.y;
  const int lin = blockIdx.y * gx + blockIdx.x;
  const int swz = (lin & 7) * (nwg >> 3) + (lin >> 3);
  const int bm = (swz / gx) * BM, bn = (swz % gx) * BN;

  auto stage = [&](int buf, int k0){
#pragma unroll
    for (int u = 0; u < NC; ++u){
      int c = u * 512 + t;
      if (c < ACH){
        int r = c >> 3, q = (c & 7) ^ (r & 7);
        gload_lds16(A + (size_t)(bm + r) * K + k0 + q * 8, &As[buf][c * 8]);
      } else {
        int c2 = c - ACH;
        if (c2 >= BCH) c2 -= BCH;
        int r = c2 >> 3, q = (c2 & 7) ^ (r & 7);
        gload_lds16(Bt + (size_t)(bn + r) * K + k0 + q * 8, &Bs[buf][c2 * 8]);
      }
    }
  };
  auto rd = [&](const char* base, int row, int q)->bf16x8 {
    return *(const bf16x8*)(base + row * 128 + ((q ^ (row & 7)) << 4));
  };

  f32x4 acc[MI][NI];
#pragma unroll
  for (int i = 0; i < MI; ++i)
#pragma unroll
    for (int j = 0; j < NI; ++j) acc[i][j] = (f32x4){0.f, 0.f, 0.f, 0.f};

  const int NIT = K / BK;
  stage(0, 0);
  stage(1, BK);
  const int qk = ks * 4 + hi;
  for (int it = 0; it < NIT; ++it){
    if (it < NIT - 1) wait_vmcnt<NC>();
    else wait_vmcnt<0>();
    __builtin_amdgcn_sched_barrier(0);
    __builtin_amdgcn_s_barrier();
    __builtin_amdgcn_sched_barrier(0);
    if (it + 2 < NIT) stage((it + 2) % DEPTH, (it + 2) * BK);
    const char* as = (const char*)As[it % DEPTH];
    const char* bs = (const char*)Bs[it % DEPTH];
    bf16x8 af[MI], bfr[NI];
#pragma unroll
    for (int i = 0; i < MI; ++i)  af[i]  = rd(as, wr * 64 + i * 16 + lo, qk);
#pragma unroll
    for (int j = 0; j < NI; ++j) bfr[j] = rd(bs, wc * 48 + j * 16 + lo, qk);
#pragma unroll
    for (int i = 0; i < MI; ++i)
#pragma unroll
      for (int j = 0; j < NI; ++j)
        acc[i][j] = __builtin_amdgcn_mfma_f32_16x16x32_bf16(af[i], bfr[j], acc[i][j], 0, 0, 0);
  }

  // ---- ks reduction (+bias) in LDS ----
  __syncthreads();
  float* ET = (float*)smem;
  if (ks == 1){
#pragma unroll
    for (int i = 0; i < MI; ++i)
#pragma unroll
      for (int j = 0; j < NI; ++j)
#pragma unroll
        for (int r = 0; r < 4; ++r)
          ET[(wr * 64 + i * 16 + hi * 4 + r) * LDE + wc * 48 + j * 16 + lo] = acc[i][j][r];
  }
  __syncthreads();
  if (ks == 0){
#pragma unroll
    for (int i = 0; i < MI; ++i)
#pragma unroll
      for (int j = 0; j < NI; ++j){
        int col_l = wc * 48 + j * 16 + lo;
        float bcol = bias[bn + col_l];
#pragma unroll
        for (int r = 0; r < 4; ++r){
          int idx = (wr * 64 + i * 16 + hi * 4 + r) * LDE + col_l;
          ET[idx] = ET[idx] + acc[i][j][r] + bcol;
        }
      }
  }
  __syncthreads();
  if constexpr (EPI == 2){
    int row = t >> 2, q = t & 3;
    const float* rrow = resid + (size_t)(bm + row) * N + bn;
    float* crow = (float*)Cout + (size_t)(bm + row) * N + bn;
#pragma unroll
    for (int k = 0; k < 6; ++k){
      int c4 = (q + k * 4) * 4;
      float4 v = *(const float4*)&ET[row * LDE + c4];
      float4 rs = *(const float4*)&rrow[c4];
      v.x += rs.x; v.y += rs.y; v.z += rs.z; v.w += rs.w;
      *(float4*)&crow[c4] = v;
    }
  } else {  // EPI == 1: GELU -> bf16
    int row = t >> 2, cq = t & 3;
    unsigned short* crow = (unsigned short*)Cout + (size_t)(bm + row) * N + bn;
#pragma unroll
    for (int s = 0; s < 3; ++s){
      int c0 = cq * 8 + s * 32;
      unsigned w4[4];
#pragma unroll
      for (int e = 0; e < 4; ++e){
        float x0 = ET[row * LDE + c0 + e * 2];
        float x1 = ET[row * LDE + c0 + e * 2 + 1];
        x0 = 0.5f * x0 * (1.f + erff(x0 * 0.70710678118f));
        x1 = 0.5f * x1 * (1.f + erff(x1 * 0.70710678118f));
        w4[e] = (unsigned)f2bf(x0) | ((unsigned)f2bf(x1) << 16);
      }
      *(uint4*)&crow[c0] = make_uint4(w4[0], w4[1], w4[2], w4[3]);
    }
  }
}

// ---- Flash attention: T14 async-stage + double-buffered K/V, 1 barrier per iter ----
__global__ __launch_bounds__(256) void attn_kernel(
    const unsigned short* __restrict__ Qs,   // [b*h][1024][64]
    const unsigned short* __restrict__ Ks,   // [b*h][1024][64]
    const unsigned short* __restrict__ Vts,  // [b*h][64][1024]  (V transposed)
    const unsigned long long* __restrict__ pm,
    unsigned short* __restrict__ o)          // [token][768]
{
  constexpr int LD = 72;
  __shared__ __align__(16) unsigned short Kl[2][64 * LD];
  __shared__ __align__(16) unsigned short Vt[2][64 * LD];
  __shared__ __align__(16) unsigned short Pl[4][16 * LD];
  const int qb = blockIdx.x, h = blockIdx.y, b = blockIdx.z;
  const int t = threadIdx.x, wid = t >> 6, lane = t & 63;
  const int lo = lane & 15, hi = lane >> 4;
  const size_t bh = (size_t)b * 12 + h;

  const unsigned short* Qg = Qs + (bh * 1024 + qb * 64 + wid * 16 + lo) * 64;
  bf16x8 qf0 = *(const bf16x8*)(Qg + hi * 8);
  bf16x8 qf1 = *(const bf16x8*)(Qg + 32 + hi * 8);

  f32x4 oacc[4];
#pragma unroll
  for (int dj = 0; dj < 4; ++dj) oacc[dj] = (f32x4){0.f, 0.f, 0.f, 0.f};
  float l_part = 0.f;

  const int srow = t >> 2, scol = (t & 3) * 16;
  const int sdst = srow * LD + scol;
  const unsigned short* kg = Ks  + bh * 65536 + srow * 64 + scol;
  const unsigned short* vg = Vts + bh * 65536 + srow * 1024 + scol;
  unsigned short* pw = &Pl[wid][0];

  bf16x8 kn0 = *(const bf16x8*)(kg);
  bf16x8 kn1 = *(const bf16x8*)(kg + 8);
  bf16x8 vn0 = *(const bf16x8*)(vg);
  bf16x8 vn1 = *(const bf16x8*)(vg + 8);
  *(bf16x8*)&Kl[0][sdst]     = kn0;
  *(bf16x8*)&Kl[0][sdst + 8] = kn1;
  *(bf16x8*)&Vt[0][sdst]     = vn0;
  *(bf16x8*)&Vt[0][sdst + 8] = vn1;
  __syncthreads();

  for (int kt = 0; kt < 16; ++kt){
    const int cur = kt & 1;
    if (kt + 1 < 16){
      kn0 = *(const bf16x8*)(kg + (kt + 1) * 4096);
      kn1 = *(const bf16x8*)(kg + (kt + 1) * 4096 + 8);
      vn0 = *(const bf16x8*)(vg + (kt + 1) * 64);
      vn1 = *(const bf16x8*)(vg + (kt + 1) * 64 + 8);
    }

    f32x4 s[4];
#pragma unroll
    for (int nj = 0; nj < 4; ++nj) s[nj] = (f32x4){0.f, 0.f, 0.f, 0.f};
#pragma unroll
    for (int kk = 0; kk < 2; ++kk){
      bf16x8 q = kk ? qf1 : qf0;
#pragma unroll
      for (int nj = 0; nj < 4; ++nj){
        bf16x8 kf = *(const bf16x8*)&Kl[cur][(nj * 16 + lo) * LD + kk * 32 + hi * 8];
        s[nj] = __builtin_amdgcn_mfma_f32_16x16x32_bf16(kf, q, s[nj], 0, 0, 0);
      }
    }

    unsigned long long w = pm[b * 16 + kt] >> (hi * 4);
#pragma unroll
    for (int nj = 0; nj < 4; ++nj){
      float p[4];
#pragma unroll
      for (int r = 0; r < 4; ++r){
        float e = __expf(fmaf(s[nj][r], 0.125f, -16.0f));
        e = ((unsigned)(w >> (nj * 16 + r)) & 1u) ? e : 0.0f;
        l_part += e;
        p[r] = e;
      }
      unsigned w0 = cvt_pk_bf16(p[0], p[1]);
      unsigned w1 = cvt_pk_bf16(p[2], p[3]);
      *(uint2*)&pw[lo * LD + nj * 16 + hi * 4] = make_uint2(w0, w1);
    }
    asm volatile("" ::: "memory");
    bf16x8 pf0 = *(const bf16x8*)&pw[lo * LD + hi * 8];
    bf16x8 pf1 = *(const bf16x8*)&pw[lo * LD + 32 + hi * 8];
#pragma unroll
    for (int kk = 0; kk < 2; ++kk){
      bf16x8 pf = kk ? pf1 : pf0;
#pragma unroll
      for (int dj = 0; dj < 4; ++dj){
        bf16x8 vf = *(const bf16x8*)&Vt[cur][(dj * 16 + lo) * LD + kk * 32 + hi * 8];
        oacc[dj] = __builtin_amdgcn_mfma_f32_16x16x32_bf16(vf, pf, oacc[dj], 0, 0, 0);
      }
    }

    if (kt + 1 < 16){
      *(bf16x8*)&Kl[cur ^ 1][sdst]     = kn0;
      *(bf16x8*)&Kl[cur ^ 1][sdst + 8] = kn1;
      *(bf16x8*)&Vt[cur ^ 1][sdst]     = vn0;
      *(bf16x8*)&Vt[cur ^ 1][sdst + 8] = vn1;
    }
    __syncthreads();
  }

  float l = l_part;
  l += __shfl_xor(l, 16, 64);
  l += __shfl_xor(l, 32, 64);
  float inv = 1.0f / l;
  size_t orow = (size_t)b * 1024 + qb * 64 + wid * 16 + lo;
#pragma unroll
  for (int dj = 0; dj < 4; ++dj){
    unsigned w0 = (unsigned)f2bf(oacc[dj][0] * inv) | ((unsigned)f2bf(oacc[dj][1] * inv) << 16);
    unsigned w1 = (unsigned)f2bf(oacc[dj][2] * inv) | ((unsigned)f2bf(oacc[dj][3] * inv) << 16);
    *(uint2*)&o[orow * DIM + h * 64 + dj * 16 + hi * 4] = make_uint2(w0, w1);
  }
}

extern "C" void kernel_launch(void* const* d_in, const int* in_sizes, int n_in,
                              void* d_out, int out_size, void* d_ws, size_t ws_size,
                              hipStream_t stream)
{
  const float* x      = (const float*)d_in[0];
  const int*   amask  = (const int*)  d_in[1];
  const float* ln1_g  = (const float*)d_in[2];
  const float* ln1_b  = (const float*)d_in[3];
  const float* ln2_g  = (const float*)d_in[4];
  const float* ln2_b  = (const float*)d_in[5];
  const float* w_qkv  = (const float*)d_in[6];
  const float* b_qkv  = (const float*)d_in[7];
  const float* w_proj = (const float*)d_in[8];
  const float* b_proj = (const float*)d_in[9];
  const float* w_fc1  = (const float*)d_in[10];
  const float* b_fc1  = (const float*)d_in[11];
  const float* w_fc2  = (const float*)d_in[12];
  const float* b_fc2  = (const float*)d_in[13];
  float* outp = (float*)d_out;

  char* w = (char*)d_ws;
  auto alloc = [&](size_t bytes){ char* p = w; w += (bytes + 255) & ~(size_t)255; return p; };

  char* p0 = alloc((size_t)4 * 6291456);
  unsigned short* Qs   = (unsigned short*)p0;
  unsigned short* Ks   = (unsigned short*)(p0 + 6291456);
  unsigned short* Vts  = (unsigned short*)(p0 + 2 * 6291456);
  unsigned short* o_bf = (unsigned short*)(p0 + 3 * 6291456);
  unsigned short* a1   = (unsigned short*)p0;
  unsigned short* h_bf = (unsigned short*)alloc((size_t)NTOK * DIM * 2);
  unsigned short* h2   = h_bf;
  float*          x1   = (float*)alloc((size_t)NTOK * DIM * 4);
  unsigned short* wqkvT = (unsigned short*)alloc((size_t)3 * DIM * DIM * 2);
  unsigned short* wprojT= (unsigned short*)alloc((size_t)DIM * DIM * 2);
  unsigned short* wfc1T = (unsigned short*)alloc((size_t)HID * DIM * 2);
  unsigned short* wfc2T = (unsigned short*)alloc((size_t)DIM * HID * 2);
  unsigned long long* pmask = (unsigned long long*)alloc(4 * 16 * 8);

  transpose4_kernel<<<6912, 256, 0, stream>>>(w_qkv, w_proj, w_fc1, w_fc2,
                                              wqkvT, wprojT, wfc1T, wfc2T);
  pack_mask_kernel<<<4, 256, 0, stream>>>(amask, pmask);

  ln_kernel<<<NTOK / 4, 256, 0, stream>>>(x, ln1_g, ln1_b, h_bf);
  gemm_qkv_kernel<<<dim3(2304 / 96, NTOK / 128), 256, 0, stream>>>(
      h_bf, wqkvT, b_qkv, Qs, Ks, Vts, NTOK, 2304, DIM);
  attn_kernel<<<dim3(16, 12, 4), 256, 0, stream>>>(Qs, Ks, Vts, pmask, o_bf);
  gemm_ks_kernel<2><<<dim3(DIM / 96, NTOK / 128), 512, 0, stream>>>(
      o_bf, wprojT, b_proj, x, x1, NTOK, DIM, DIM);
  ln_kernel<<<NTOK / 4, 256, 0, stream>>>(x1, ln2_g, ln2_b, h2);
  gemm_ks_kernel<1><<<dim3(HID / 96, NTOK / 128), 512, 0, stream>>>(
      h2, wfc1T, b_fc1, nullptr, a1, NTOK, HID, DIM);
  gemm_ks_kernel<2><<<dim3(DIM / 96, NTOK / 128), 512, 0, stream>>>(
      a1, wfc2T, b_fc2, x1, outp, NTOK, DIM, HID);
}

// Round 13
// 157.145 us; speedup vs baseline: 1.0888x; 1.0888x over previous
//
#include <hip/hip_runtime.h>

#define DIM 768
#define NTOK 4096
#define HID 3072

typedef __attribute__((ext_vector_type(8))) short bf16x8;
typedef __attribute__((ext_vector_type(4))) float f32x4;

__device__ inline unsigned short f2bf(float f){
  unsigned u = __float_as_uint(f);
  u += 0x7fff + ((u >> 16) & 1);
  return (unsigned short)(u >> 16);
}
__device__ inline unsigned cvt_pk_bf16(float a, float b){
  unsigned r;
  asm("v_cvt_pk_bf16_f32 %0, %1, %2" : "=v"(r) : "v"(a), "v"(b));
  return r;
}
__device__ inline void gload_lds16(const void* g, void* l){
  __builtin_amdgcn_global_load_lds(
      (const __attribute__((address_space(1))) unsigned int*)g,
      (__attribute__((address_space(3))) unsigned int*)l, 16, 0, 0);
}
template<int N> __device__ inline void wait_vmcnt(){
  if constexpr (N == 0) asm volatile("s_waitcnt vmcnt(0)" ::: "memory");
  else if constexpr (N == 4) asm volatile("s_waitcnt vmcnt(4)" ::: "memory");
  else if constexpr (N == 8) asm volatile("s_waitcnt vmcnt(8)" ::: "memory");
  else static_assert(N == 0, "unsupported vmcnt");
}
// 64B-row tiles: chunk-level XOR (2-way classes on fragment reads)
__device__ inline int swz_read(int row, int hi){
  return (row * 64 + hi * 16) ^ ((row & 7) << 4);
}

// ---------------- LayerNorm: fp32 in -> bf16 out, 1 wave per 768-row ----------------
__global__ __launch_bounds__(256) void ln_kernel(const float* __restrict__ x,
    const float* __restrict__ g, const float* __restrict__ b,
    unsigned short* __restrict__ out)
{
  int row = blockIdx.x * 4 + (threadIdx.x >> 6);
  int lane = threadIdx.x & 63;
  const float* xr = x + (size_t)row * DIM;
  float4 v[3];
  float s = 0.f, s2 = 0.f;
#pragma unroll
  for (int j = 0; j < 3; ++j){
    v[j] = *(const float4*)(xr + j * 256 + lane * 4);
    s  += v[j].x + v[j].y + v[j].z + v[j].w;
    s2 += v[j].x*v[j].x + v[j].y*v[j].y + v[j].z*v[j].z + v[j].w*v[j].w;
  }
#pragma unroll
  for (int m = 1; m < 64; m <<= 1){ s += __shfl_xor(s, m, 64); s2 += __shfl_xor(s2, m, 64); }
  float mu  = s * (1.f / 768.f);
  float var = s2 * (1.f / 768.f) - mu * mu;
  float inv = rsqrtf(var + 1e-5f);
#pragma unroll
  for (int j = 0; j < 3; ++j){
    int c0 = j * 256 + lane * 4;
    float vv[4] = { v[j].x, v[j].y, v[j].z, v[j].w };
    ushort4 o4;
    o4.x = f2bf((vv[0] - mu) * inv * g[c0 + 0] + b[c0 + 0]);
    o4.y = f2bf((vv[1] - mu) * inv * g[c0 + 1] + b[c0 + 1]);
    o4.z = f2bf((vv[2] - mu) * inv * g[c0 + 2] + b[c0 + 2]);
    o4.w = f2bf((vv[3] - mu) * inv * g[c0 + 3] + b[c0 + 3]);
    *(ushort4*)(out + (size_t)row * DIM + c0) = o4;
  }
}

// ------- fused weight transposes: 4 weights, W[K][N] fp32 -> Wt[N][K] bf16 ----------
__global__ __launch_bounds__(256) void transpose4_kernel(
    const float* __restrict__ w_qkv, const float* __restrict__ w_proj,
    const float* __restrict__ w_fc1, const float* __restrict__ w_fc2,
    unsigned short* __restrict__ tq, unsigned short* __restrict__ tp,
    unsigned short* __restrict__ t1, unsigned short* __restrict__ t2)
{
  __shared__ __align__(16) unsigned short tile[32][33];
  int id = blockIdx.x;
  const float* W; unsigned short* Wt; int K, N, tx_n;
  if (id < 1728)      { W = w_qkv;  Wt = tq; K = 768;  N = 2304; tx_n = 72; }
  else if (id < 2304) { W = w_proj; Wt = tp; K = 768;  N = 768;  tx_n = 24; id -= 1728; }
  else if (id < 4608) { W = w_fc1;  Wt = t1; K = 768;  N = 3072; tx_n = 96; id -= 2304; }
  else                { W = w_fc2;  Wt = t2; K = 3072; N = 768;  tx_n = 24; id -= 4608; }
  int n0 = (id % tx_n) * 32, k0 = (id / tx_n) * 32;
  int tx = threadIdx.x & 31, ty = threadIdx.x >> 5;
#pragma unroll
  for (int i = 0; i < 32; i += 8)
    tile[ty + i][tx] = f2bf(W[(size_t)(k0 + ty + i) * N + n0 + tx]);
  __syncthreads();
#pragma unroll
  for (int i = 0; i < 32; i += 8)
    Wt[(size_t)(n0 + ty + i) * K + k0 + tx] = tile[tx][ty + i];
}

// ---------------- pack attention mask into bit-words: pm[b][kt] bit k = mask!=0 ------
__global__ __launch_bounds__(256) void pack_mask_kernel(const int* __restrict__ am,
    unsigned long long* __restrict__ pm)
{
  int lane = threadIdx.x & 63, w = threadIdx.x >> 6, b = blockIdx.x;
  for (int k = w; k < 16; k += 4){
    unsigned long long m = __ballot(am[b * 1024 + k * 64 + lane] != 0);
    if (lane == 0) pm[b * 16 + k] = m;
  }
}

// ------- QKV GEMM: 256 thr, BM=128 x BN=96, rotated 3-buffer, split epilogue --------
// grid (2304/96=24, 32) = 768 blocks = exactly 3/CU balanced.
__global__ __launch_bounds__(256) void gemm_qkv_kernel(
    const unsigned short* __restrict__ A,   // [M][768] bf16
    const unsigned short* __restrict__ Bt,  // [2304][768] bf16
    const float* __restrict__ bias,         // [2304]
    unsigned short* __restrict__ q_out,
    unsigned short* __restrict__ k_out,
    unsigned short* __restrict__ v_out,
    int M, int N, int K)
{
  constexpr int BM = 128, BN = 96, BK = 32, DEPTH = 3;
  constexpr int MI = 4, NI = 3;              // wave tile 64x48, wave grid 2x2
  constexpr int SMEM_B = DEPTH * (BM + BN) * BK * 2;   // 43008 B
  __shared__ __align__(16) char smem[SMEM_B];
  auto As = (unsigned short(*)[BM * BK])smem;
  auto Bs = (unsigned short(*)[BN * BK])(smem + DEPTH * BM * BK * 2);
  const int t = threadIdx.x, lane = t & 63, wid = t >> 6;
  const int lo = lane & 15, hi = lane >> 4;
  const int wr = wid >> 1, wc = wid & 1;

  const int gx = gridDim.x;
  const int nwg = gx * gridDim.y;
  const int lin = blockIdx.y * gx + blockIdx.x;
  const int swz = (lin & 7) * (nwg >> 3) + (lin >> 3);
  const int bm = (swz / gx) * BM, bn = (swz % gx) * BN;

  // hoisted staging sources; chunk map: c<512 -> A chunk c; else B chunk (wrap >=384)
  const unsigned short *p0, *p1, *p2, *p3;
  int d3;
  {
    int c, rp, r, q;
    c = t;       rp = c >> 2; r = rp ^ ((rp >> 2) & 1); q = (c & 3) ^ (r & 3);
    p0 = A  + (size_t)(bm + r) * K + q * 8;
    c = 256 + t; rp = c >> 2; r = rp ^ ((rp >> 2) & 1); q = (c & 3) ^ (r & 3);
    p1 = A  + (size_t)(bm + r) * K + q * 8;
    c = t;       rp = c >> 2; r = rp ^ ((rp >> 2) & 1); q = (c & 3) ^ (r & 3);
    p2 = Bt + (size_t)(bn + r) * K + q * 8;
    int c2w = (t < 128) ? 256 + t : t - 128;           // benign duplicate for t>=128
    c = c2w;     rp = c >> 2; r = rp ^ ((rp >> 2) & 1); q = (c & 3) ^ (r & 3);
    p3 = Bt + (size_t)(bn + r) * K + q * 8;
    d3 = c2w * 8;
  }
  int ofsA[MI], ofsB[NI];
#pragma unroll
  for (int i = 0; i < MI; ++i) ofsA[i] = swz_read(wr * 64 + i * 16 + lo, hi);
#pragma unroll
  for (int j = 0; j < NI; ++j) ofsB[j] = swz_read(wc * 48 + j * 16 + lo, hi);

  f32x4 acc[MI][NI];
#pragma unroll
  for (int i = 0; i < MI; ++i)
#pragma unroll
    for (int j = 0; j < NI; ++j) acc[i][j] = (f32x4){0.f, 0.f, 0.f, 0.f};

  const int NIT = K / BK;                    // 24, % 3 == 0
  auto stagefull = [&](int buf) __attribute__((always_inline)) {
    gload_lds16(p0, &As[buf][t * 8]);
    gload_lds16(p1, &As[buf][(256 + t) * 8]);
    gload_lds16(p2, &Bs[buf][t * 8]);
    gload_lds16(p3, &Bs[buf][d3]);
    p0 += BK; p1 += BK; p2 += BK; p3 += BK;
  };
  auto kbody = [&](int it, int RB, int WB) __attribute__((always_inline)) {
    if (it < NIT - 1) wait_vmcnt<4>(); else wait_vmcnt<0>();
    __builtin_amdgcn_sched_barrier(0);
    __builtin_amdgcn_s_barrier();
    __builtin_amdgcn_sched_barrier(0);
    if (it + 2 < NIT) stagefull(WB);
    const char* as = (const char*)As[RB];
    const char* bs = (const char*)Bs[RB];
    bf16x8 af[MI], bfr[NI];
#pragma unroll
    for (int i = 0; i < MI; ++i) af[i]  = *(const bf16x8*)(as + ofsA[i]);
#pragma unroll
    for (int j = 0; j < NI; ++j) bfr[j] = *(const bf16x8*)(bs + ofsB[j]);
    __builtin_amdgcn_s_setprio(1);
#pragma unroll
    for (int i = 0; i < MI; ++i)
#pragma unroll
      for (int j = 0; j < NI; ++j)
        acc[i][j] = __builtin_amdgcn_mfma_f32_16x16x32_bf16(af[i], bfr[j], acc[i][j], 0, 0, 0);
    __builtin_amdgcn_s_setprio(0);
  };

  stagefull(0);
  stagefull(1);
  for (int it = 0; it < NIT; it += 3){
    kbody(it,     0, 2);
    kbody(it + 1, 1, 0);
    kbody(it + 2, 2, 1);
  }

  __syncthreads();   // staging reads done; smem reusable

  // ---- split epilogue. acc: col=lane&15, row=(lane>>4)*4+r ----
  const int part = bn / 768;                 // 0=Q 1=K 2=V (uniform; 768 % 96 == 0)
  const int cloc = bn % 768;
  const int bb = bm >> 10, n0b = bm & 1023;
  unsigned short* ET = (unsigned short*)smem;
  if (part < 2){
    constexpr int LDE = 104;                 // 128 x 104 bf16 = 26.6KB
#pragma unroll
    for (int i = 0; i < MI; ++i)
#pragma unroll
      for (int j = 0; j < NI; ++j){
        int col_l = wc * 48 + j * 16 + lo;
        float bcol = bias[bn + col_l];
#pragma unroll
        for (int r = 0; r < 4; ++r)
          ET[(wr * 64 + i * 16 + hi * 4 + r) * LDE + col_l] = f2bf(acc[i][j][r] + bcol);
      }
    __syncthreads();
    unsigned short* dst0 = (part == 0) ? q_out : k_out;
#pragma unroll
    for (int p = 0; p < 8; ++p){
      int row = p * 16 + (t >> 4), chunk = t & 15;
      if (chunk < 12){
        int col = cloc + chunk * 8, hh = col >> 6, d0 = col & 63;
        *(bf16x8*)&dst0[((size_t)(bb * 12 + hh)) * 65536 + (n0b + row) * 64 + d0] =
            *(const bf16x8*)&ET[row * LDE + chunk * 8];
      }
    }
  } else {
    constexpr int LDV = 136;                 // 96 x 136 bf16 = 26.1KB, col-major store
#pragma unroll
    for (int i = 0; i < MI; ++i)
#pragma unroll
      for (int j = 0; j < NI; ++j){
        int col_l = wc * 48 + j * 16 + lo;
        float bcol = bias[bn + col_l];
#pragma unroll
        for (int r = 0; r < 4; ++r)
          ET[col_l * LDV + wr * 64 + i * 16 + hi * 4 + r] = f2bf(acc[i][j][r] + bcol);
      }
    __syncthreads();
#pragma unroll
    for (int p = 0; p < 6; ++p){
      int colg = p * 16 + (t >> 4), chunk = t & 15;
      int col = cloc + colg, hh = col >> 6, d = col & 63;
      *(bf16x8*)&v_out[((size_t)(bb * 12 + hh)) * 65536 + (size_t)d * 1024 + n0b + chunk * 8] =
          *(const bf16x8*)&ET[colg * LDV + chunk * 8];
    }
  }
}

// ------- 256-thread MFMA GEMM (FC1): 128x128, rotated 3-buffer, hoisted addressing --
// EPI: 0 bias->bf16, 1 bias+GELU->bf16.  Requires (K/32) % 3 == 0.
template<int EPI>
__global__ __launch_bounds__(256) void gemm_kernel(
    const unsigned short* __restrict__ A,   // [M][K] bf16
    const unsigned short* __restrict__ Bt,  // [N][K] bf16
    const float* __restrict__ bias,         // [N]
    unsigned short* __restrict__ C,         // [M][N] bf16
    int M, int N, int K)
{
  constexpr int BM = 128, BN = 128, BK = 32, WM = 64, WN = 64, DEPTH = 3;
  constexpr int MI = WM / 16, NI = WN / 16;  // 4, 4
  constexpr int SMEM_B = DEPTH * (BM + BN) * BK * 2;   // 48KB
  __shared__ __align__(16) char smem[SMEM_B];
  auto As = (unsigned short(*)[BM * BK])smem;
  auto Bs = (unsigned short(*)[BN * BK])(smem + DEPTH * BM * BK * 2);
  const int t = threadIdx.x, lane = t & 63, wid = t >> 6;
  const int lo = lane & 15, hi = lane >> 4;
  const int wr = wid >> 1, wc = wid & 1;

  const int gx = gridDim.x;
  const int nwg = gx * gridDim.y;
  const int lin = blockIdx.y * gx + blockIdx.x;
  const int swz = (lin & 7) * (nwg >> 3) + (lin >> 3);
  const int bm = (swz / gx) * BM, bn = (swz % gx) * BN;

  const unsigned short *a0, *a1, *b0, *b1;
  {
    int rp = t >> 2, r = rp ^ ((rp >> 2) & 1), q = (t & 3) ^ (r & 3);
    a0 = A  + (size_t)(bm + r) * K + q * 8;
    b0 = Bt + (size_t)(bn + r) * K + q * 8;
    int c = 256 + t;
    rp = c >> 2; r = rp ^ ((rp >> 2) & 1); q = (c & 3) ^ (r & 3);
    a1 = A  + (size_t)(bm + r) * K + q * 8;
    b1 = Bt + (size_t)(bn + r) * K + q * 8;
  }
  int ofsA[MI], ofsB[NI];
#pragma unroll
  for (int i = 0; i < MI; ++i) ofsA[i] = swz_read(wr * WM + i * 16 + lo, hi);
#pragma unroll
  for (int j = 0; j < NI; ++j) ofsB[j] = swz_read(wc * WN + j * 16 + lo, hi);

  f32x4 acc[MI][NI];
#pragma unroll
  for (int i = 0; i < MI; ++i)
#pragma unroll
    for (int j = 0; j < NI; ++j) acc[i][j] = (f32x4){0.f, 0.f, 0.f, 0.f};

  const int NIT = K / BK;                  // 24; % 3 == 0
  auto stagefull = [&](int buf) __attribute__((always_inline)) {
    gload_lds16(a0, &As[buf][t * 8]);
    gload_lds16(a1, &As[buf][(256 + t) * 8]);
    gload_lds16(b0, &Bs[buf][t * 8]);
    gload_lds16(b1, &Bs[buf][(256 + t) * 8]);
    a0 += BK; a1 += BK; b0 += BK; b1 += BK;
  };
  auto kbody = [&](int it, int RB, int WB) __attribute__((always_inline)) {
    if (it < NIT - 1) wait_vmcnt<4>(); else wait_vmcnt<0>();
    __builtin_amdgcn_sched_barrier(0);
    __builtin_amdgcn_s_barrier();
    __builtin_amdgcn_sched_barrier(0);
    if (it + 2 < NIT) stagefull(WB);
    const char* as = (const char*)As[RB];
    const char* bs = (const char*)Bs[RB];
    bf16x8 af[MI], bfr[NI];
#pragma unroll
    for (int i = 0; i < MI; ++i) af[i]  = *(const bf16x8*)(as + ofsA[i]);
#pragma unroll
    for (int j = 0; j < NI; ++j) bfr[j] = *(const bf16x8*)(bs + ofsB[j]);
    __builtin_amdgcn_s_setprio(1);
#pragma unroll
    for (int i = 0; i < MI; ++i)
#pragma unroll
      for (int j = 0; j < NI; ++j)
        acc[i][j] = __builtin_amdgcn_mfma_f32_16x16x32_bf16(af[i], bfr[j], acc[i][j], 0, 0, 0);
    __builtin_amdgcn_s_setprio(0);
  };

  stagefull(0);
  stagefull(1);
  for (int it = 0; it < NIT; it += 3){
    kbody(it,     0, 2);
    kbody(it + 1, 1, 0);
    kbody(it + 2, 2, 1);
  }

  __syncthreads();   // staging reads done; smem reusable for the epilogue

  constexpr int LDE = BN + 8;            // 136 bf16, 272 B row
  unsigned short* ET = (unsigned short*)smem;
#pragma unroll
  for (int i = 0; i < MI; ++i)
#pragma unroll
    for (int j = 0; j < NI; ++j){
      float bcol = bias[bn + wc * WN + j * 16 + lo];
#pragma unroll
      for (int r = 0; r < 4; ++r){
        float v = acc[i][j][r] + bcol;
        if constexpr (EPI == 1) v = 0.5f * v * (1.f + erff(v * 0.70710678118f));
        ET[(wr * WM + i * 16 + hi * 4 + r) * LDE + wc * WN + j * 16 + lo] = f2bf(v);
      }
    }
  __syncthreads();
#pragma unroll
  for (int p = 0; p < BM / 16; ++p){     // 16 lanes x 16B = 256B-contiguous row runs
    int row = p * 16 + (t >> 4), chunk = t & 15;
    *(bf16x8*)&C[(size_t)(bm + row) * N + bn + chunk * 8] =
        *(const bf16x8*)&ET[row * LDE + chunk * 8];
  }
}

// ------- N=768 GEMM (proj, FC2): K-split-in-block, 512 thr, BM=128 x BN=96 ----------
__global__ __launch_bounds__(512) void gemm_ks_kernel(
    const unsigned short* __restrict__ A,   // [M][K] bf16
    const unsigned short* __restrict__ Bt,  // [N][K] bf16
    const float* __restrict__ bias,         // [N]
    const float* __restrict__ resid,        // [M][N]
    float* __restrict__ C,                  // [M][N]
    int M, int N, int K)
{
  constexpr int BM = 128, BN = 96, BK = 64, DEPTH = 3;
  constexpr int MI = 4, NI = 3;
  constexpr int ACH = BM * BK / 8;         // 1024
  constexpr int BCH = BN * BK / 8;         // 768
  constexpr int NC = 4;
  constexpr int TILE_A = BM * BK * 2, TILE_B = BN * BK * 2;
  constexpr int LDE = BN + 4;              // 100 floats
  constexpr int SMEM_B = (DEPTH * (TILE_A + TILE_B) > BM * LDE * 4)
                       ?  DEPTH * (TILE_A + TILE_B) : BM * LDE * 4;   // 84KB
  __shared__ __align__(16) char smem[SMEM_B];
  auto As = (unsigned short(*)[BM * BK])smem;
  auto Bs = (unsigned short(*)[BN * BK])(smem + DEPTH * TILE_A);
  const int t = threadIdx.x, lane = t & 63, wid = t >> 6;
  const int lo = lane & 15, hi = lane >> 4;
  const int ks = wid & 1, wc = (wid >> 1) & 1, wr = wid >> 2;

  const int gx = gridDim.x;
  const int nwg = gx * gridDim.y;
  const int lin = blockIdx.y * gx + blockIdx.x;
  const int swz = (lin & 7) * (nwg >> 3) + (lin >> 3);
  const int bm = (swz / gx) * BM, bn = (swz % gx) * BN;

  auto stage = [&](int buf, int k0){
#pragma unroll
    for (int u = 0; u < NC; ++u){
      int c = u * 512 + t;
      if (c < ACH){
        int r = c >> 3, q = (c & 7) ^ (r & 7);
        gload_lds16(A + (size_t)(bm + r) * K + k0 + q * 8, &As[buf][c * 8]);
      } else {
        int c2 = c - ACH;
        if (c2 >= BCH) c2 -= BCH;
        int r = c2 >> 3, q = (c2 & 7) ^ (r & 7);
        gload_lds16(Bt + (size_t)(bn + r) * K + k0 + q * 8, &Bs[buf][c2 * 8]);
      }
    }
  };
  auto rd = [&](const char* base, int row, int q)->bf16x8 {
    return *(const bf16x8*)(base + row * 128 + ((q ^ (row & 7)) << 4));
  };

  f32x4 acc[MI][NI];
#pragma unroll
  for (int i = 0; i < MI; ++i)
#pragma unroll
    for (int j = 0; j < NI; ++j) acc[i][j] = (f32x4){0.f, 0.f, 0.f, 0.f};

  const int NIT = K / BK;                  // 12 (proj) / 48 (FC2)
  stage(0, 0);
  stage(1, BK);
  const int qk = ks * 4 + hi;
  for (int it = 0; it < NIT; ++it){
    if (it < NIT - 1) wait_vmcnt<NC>();
    else wait_vmcnt<0>();
    __builtin_amdgcn_sched_barrier(0);
    __builtin_amdgcn_s_barrier();
    __builtin_amdgcn_sched_barrier(0);
    if (it + 2 < NIT) stage((it + 2) % DEPTH, (it + 2) * BK);
    const char* as = (const char*)As[it % DEPTH];
    const char* bs = (const char*)Bs[it % DEPTH];
    bf16x8 af[MI], bfr[NI];
#pragma unroll
    for (int i = 0; i < MI; ++i)  af[i]  = rd(as, wr * 64 + i * 16 + lo, qk);
#pragma unroll
    for (int j = 0; j < NI; ++j) bfr[j] = rd(bs, wc * 48 + j * 16 + lo, qk);
    __builtin_amdgcn_s_setprio(1);
#pragma unroll
    for (int i = 0; i < MI; ++i)
#pragma unroll
      for (int j = 0; j < NI; ++j)
        acc[i][j] = __builtin_amdgcn_mfma_f32_16x16x32_bf16(af[i], bfr[j], acc[i][j], 0, 0, 0);
    __builtin_amdgcn_s_setprio(0);
  }

  // ---- ks reduction (+bias) in LDS ----
  __syncthreads();
  float* ET = (float*)smem;
  if (ks == 1){
#pragma unroll
    for (int i = 0; i < MI; ++i)
#pragma unroll
      for (int j = 0; j < NI; ++j)
#pragma unroll
        for (int r = 0; r < 4; ++r)
          ET[(wr * 64 + i * 16 + hi * 4 + r) * LDE + wc * 48 + j * 16 + lo] = acc[i][j][r];
  }
  __syncthreads();
  if (ks == 0){
#pragma unroll
    for (int i = 0; i < MI; ++i)
#pragma unroll
      for (int j = 0; j < NI; ++j){
        int col_l = wc * 48 + j * 16 + lo;
        float bcol = bias[bn + col_l];
#pragma unroll
        for (int r = 0; r < 4; ++r){
          int idx = (wr * 64 + i * 16 + hi * 4 + r) * LDE + col_l;
          ET[idx] = ET[idx] + acc[i][j][r] + bcol;
        }
      }
  }
  __syncthreads();
  {
    int row = t >> 2, q = t & 3;
    const float* rrow = resid + (size_t)(bm + row) * N + bn;
    float* crow = C + (size_t)(bm + row) * N + bn;
#pragma unroll
    for (int k = 0; k < 6; ++k){
      int c4 = (q + k * 4) * 4;
      float4 v = *(const float4*)&ET[row * LDE + c4];
      float4 rs = *(const float4*)&rrow[c4];
      v.x += rs.x; v.y += rs.y; v.z += rs.z; v.w += rs.w;
      *(float4*)&crow[c4] = v;
    }
  }
}

// ---- Flash attention: T14 async-stage + double-buffered K/V, 1 barrier per iter ----
__global__ __launch_bounds__(256) void attn_kernel(
    const unsigned short* __restrict__ Qs,   // [b*h][1024][64]
    const unsigned short* __restrict__ Ks,   // [b*h][1024][64]
    const unsigned short* __restrict__ Vts,  // [b*h][64][1024]  (V transposed)
    const unsigned long long* __restrict__ pm,
    unsigned short* __restrict__ o)          // [token][768]
{
  constexpr int LD = 72;
  __shared__ __align__(16) unsigned short Kl[2][64 * LD];
  __shared__ __align__(16) unsigned short Vt[2][64 * LD];
  __shared__ __align__(16) unsigned short Pl[4][16 * LD];
  const int qb = blockIdx.x, h = blockIdx.y, b = blockIdx.z;
  const int t = threadIdx.x, wid = t >> 6, lane = t & 63;
  const int lo = lane & 15, hi = lane >> 4;
  const size_t bh = (size_t)b * 12 + h;

  const unsigned short* Qg = Qs + (bh * 1024 + qb * 64 + wid * 16 + lo) * 64;
  bf16x8 qf0 = *(const bf16x8*)(Qg + hi * 8);
  bf16x8 qf1 = *(const bf16x8*)(Qg + 32 + hi * 8);

  f32x4 oacc[4];
#pragma unroll
  for (int dj = 0; dj < 4; ++dj) oacc[dj] = (f32x4){0.f, 0.f, 0.f, 0.f};
  float l_part = 0.f;

  const int srow = t >> 2, scol = (t & 3) * 16;
  const int sdst = srow * LD + scol;
  const unsigned short* kg = Ks  + bh * 65536 + srow * 64 + scol;
  const unsigned short* vg = Vts + bh * 65536 + srow * 1024 + scol;
  unsigned short* pw = &Pl[wid][0];

  bf16x8 kn0 = *(const bf16x8*)(kg);
  bf16x8 kn1 = *(const bf16x8*)(kg + 8);
  bf16x8 vn0 = *(const bf16x8*)(vg);
  bf16x8 vn1 = *(const bf16x8*)(vg + 8);
  *(bf16x8*)&Kl[0][sdst]     = kn0;
  *(bf16x8*)&Kl[0][sdst + 8] = kn1;
  *(bf16x8*)&Vt[0][sdst]     = vn0;
  *(bf16x8*)&Vt[0][sdst + 8] = vn1;
  __syncthreads();

  for (int kt = 0; kt < 16; ++kt){
    const int cur = kt & 1;
    if (kt + 1 < 16){
      kn0 = *(const bf16x8*)(kg + (kt + 1) * 4096);
      kn1 = *(const bf16x8*)(kg + (kt + 1) * 4096 + 8);
      vn0 = *(const bf16x8*)(vg + (kt + 1) * 64);
      vn1 = *(const bf16x8*)(vg + (kt + 1) * 64 + 8);
    }

    f32x4 s[4];
#pragma unroll
    for (int nj = 0; nj < 4; ++nj) s[nj] = (f32x4){0.f, 0.f, 0.f, 0.f};
    __builtin_amdgcn_s_setprio(1);
#pragma unroll
    for (int kk = 0; kk < 2; ++kk){
      bf16x8 q = kk ? qf1 : qf0;
#pragma unroll
      for (int nj = 0; nj < 4; ++nj){
        bf16x8 kf = *(const bf16x8*)&Kl[cur][(nj * 16 + lo) * LD + kk * 32 + hi * 8];
        s[nj] = __builtin_amdgcn_mfma_f32_16x16x32_bf16(kf, q, s[nj], 0, 0, 0);
      }
    }
    __builtin_amdgcn_s_setprio(0);

    unsigned long long w = pm[b * 16 + kt] >> (hi * 4);
#pragma unroll
    for (int nj = 0; nj < 4; ++nj){
      float p[4];
#pragma unroll
      for (int r = 0; r < 4; ++r){
        float e = __expf(fmaf(s[nj][r], 0.125f, -16.0f));
        e = ((unsigned)(w >> (nj * 16 + r)) & 1u) ? e : 0.0f;
        l_part += e;
        p[r] = e;
      }
      unsigned w0 = cvt_pk_bf16(p[0], p[1]);
      unsigned w1 = cvt_pk_bf16(p[2], p[3]);
      *(uint2*)&pw[lo * LD + nj * 16 + hi * 4] = make_uint2(w0, w1);
    }
    asm volatile("" ::: "memory");
    bf16x8 pf0 = *(const bf16x8*)&pw[lo * LD + hi * 8];
    bf16x8 pf1 = *(const bf16x8*)&pw[lo * LD + 32 + hi * 8];
    __builtin_amdgcn_s_setprio(1);
#pragma unroll
    for (int kk = 0; kk < 2; ++kk){
      bf16x8 pf = kk ? pf1 : pf0;
#pragma unroll
      for (int dj = 0; dj < 4; ++dj){
        bf16x8 vf = *(const bf16x8*)&Vt[cur][(dj * 16 + lo) * LD + kk * 32 + hi * 8];
        oacc[dj] = __builtin_amdgcn_mfma_f32_16x16x32_bf16(vf, pf, oacc[dj], 0, 0, 0);
      }
    }
    __builtin_amdgcn_s_setprio(0);

    if (kt + 1 < 16){
      *(bf16x8*)&Kl[cur ^ 1][sdst]     = kn0;
      *(bf16x8*)&Kl[cur ^ 1][sdst + 8] = kn1;
      *(bf16x8*)&Vt[cur ^ 1][sdst]     = vn0;
      *(bf16x8*)&Vt[cur ^ 1][sdst + 8] = vn1;
    }
    __syncthreads();
  }

  float l = l_part;
  l += __shfl_xor(l, 16, 64);
  l += __shfl_xor(l, 32, 64);
  float inv = 1.0f / l;
  size_t orow = (size_t)b * 1024 + qb * 64 + wid * 16 + lo;
#pragma unroll
  for (int dj = 0; dj < 4; ++dj){
    unsigned w0 = (unsigned)f2bf(oacc[dj][0] * inv) | ((unsigned)f2bf(oacc[dj][1] * inv) << 16);
    unsigned w1 = (unsigned)f2bf(oacc[dj][2] * inv) | ((unsigned)f2bf(oacc[dj][3] * inv) << 16);
    *(uint2*)&o[orow * DIM + h * 64 + dj * 16 + hi * 4] = make_uint2(w0, w1);
  }
}

extern "C" void kernel_launch(void* const* d_in, const int* in_sizes, int n_in,
                              void* d_out, int out_size, void* d_ws, size_t ws_size,
                              hipStream_t stream)
{
  const float* x      = (const float*)d_in[0];
  const int*   amask  = (const int*)  d_in[1];
  const float* ln1_g  = (const float*)d_in[2];
  const float* ln1_b  = (const float*)d_in[3];
  const float* ln2_g  = (const float*)d_in[4];
  const float* ln2_b  = (const float*)d_in[5];
  const float* w_qkv  = (const float*)d_in[6];
  const float* b_qkv  = (const float*)d_in[7];
  const float* w_proj = (const float*)d_in[8];
  const float* b_proj = (const float*)d_in[9];
  const float* w_fc1  = (const float*)d_in[10];
  const float* b_fc1  = (const float*)d_in[11];
  const float* w_fc2  = (const float*)d_in[12];
  const float* b_fc2  = (const float*)d_in[13];
  float* outp = (float*)d_out;

  char* w = (char*)d_ws;
  auto alloc = [&](size_t bytes){ char* p = w; w += (bytes + 255) & ~(size_t)255; return p; };

  char* p0 = alloc((size_t)4 * 6291456);
  unsigned short* Qs   = (unsigned short*)p0;
  unsigned short* Ks   = (unsigned short*)(p0 + 6291456);
  unsigned short* Vts  = (unsigned short*)(p0 + 2 * 6291456);
  unsigned short* o_bf = (unsigned short*)(p0 + 3 * 6291456);
  unsigned short* a1   = (unsigned short*)p0;
  unsigned short* h_bf = (unsigned short*)alloc((size_t)NTOK * DIM * 2);
  unsigned short* h2   = h_bf;
  float*          x1   = (float*)alloc((size_t)NTOK * DIM * 4);
  unsigned short* wqkvT = (unsigned short*)alloc((size_t)3 * DIM * DIM * 2);
  unsigned short* wprojT= (unsigned short*)alloc((size_t)DIM * DIM * 2);
  unsigned short* wfc1T = (unsigned short*)alloc((size_t)HID * DIM * 2);
  unsigned short* wfc2T = (unsigned short*)alloc((size_t)DIM * HID * 2);
  unsigned long long* pmask = (unsigned long long*)alloc(4 * 16 * 8);

  transpose4_kernel<<<6912, 256, 0, stream>>>(w_qkv, w_proj, w_fc1, w_fc2,
                                              wqkvT, wprojT, wfc1T, wfc2T);
  pack_mask_kernel<<<4, 256, 0, stream>>>(amask, pmask);

  ln_kernel<<<NTOK / 4, 256, 0, stream>>>(x, ln1_g, ln1_b, h_bf);
  gemm_qkv_kernel<<<dim3(2304 / 96, NTOK / 128), 256, 0, stream>>>(
      h_bf, wqkvT, b_qkv, Qs, Ks, Vts, NTOK, 2304, DIM);
  attn_kernel<<<dim3(16, 12, 4), 256, 0, stream>>>(Qs, Ks, Vts, pmask, o_bf);
  gemm_ks_kernel<<<dim3(DIM / 96, NTOK / 128), 512, 0, stream>>>(
      o_bf, wprojT, b_proj, x, x1, NTOK, DIM, DIM);
  ln_kernel<<<NTOK / 4, 256, 0, stream>>>(x1, ln2_g, ln2_b, h2);
  gemm_kernel<1><<<dim3(HID / 128, NTOK / 128), 256, 0, stream>>>(
      h2, wfc1T, b_fc1, a1, NTOK, HID, DIM);
  gemm_ks_kernel<<<dim3(DIM / 96, NTOK / 128), 512, 0, stream>>>(
      a1, wfc2T, b_fc2, x1, outp, NTOK, DIM, HID);
}

// Round 14
// 148.926 us; speedup vs baseline: 1.1488x; 1.0552x over previous
//
#include <hip/hip_runtime.h>

#define DIM 768
#define NTOK 4096
#define HID 3072

typedef __attribute__((ext_vector_type(8))) short bf16x8;
typedef __attribute__((ext_vector_type(4))) float f32x4;

__device__ inline unsigned short f2bf(float f){
  unsigned u = __float_as_uint(f);
  u += 0x7fff + ((u >> 16) & 1);
  return (unsigned short)(u >> 16);
}
__device__ inline unsigned cvt_pk_bf16(float a, float b){
  unsigned r;
  asm("v_cvt_pk_bf16_f32 %0, %1, %2" : "=v"(r) : "v"(a), "v"(b));
  return r;
}
__device__ inline void gload_lds16(const void* g, void* l){
  __builtin_amdgcn_global_load_lds(
      (const __attribute__((address_space(1))) unsigned int*)g,
      (__attribute__((address_space(3))) unsigned int*)l, 16, 0, 0);
}
template<int N> __device__ inline void wait_vmcnt(){
  if constexpr (N == 0) asm volatile("s_waitcnt vmcnt(0)" ::: "memory");
  else if constexpr (N == 4) asm volatile("s_waitcnt vmcnt(4)" ::: "memory");
  else if constexpr (N == 8) asm volatile("s_waitcnt vmcnt(8)" ::: "memory");
  else static_assert(N == 0, "unsupported vmcnt");
}
// 64B-row tiles: chunk-level XOR (2-way classes on fragment reads)
__device__ inline int swz_read(int row, int hi){
  return (row * 64 + hi * 16) ^ ((row & 7) << 4);
}
// fast tanh-form GELU (|err| vs exact-erf GELU < ~3e-3)
__device__ inline float gelu_fast(float v){
  float u = v * (0.7978845608f + 0.0356774081f * v * v);
  float e = __expf(-2.0f * fabsf(u));
  float th = 1.0f - __fdividef(2.0f * e, 1.0f + e);
  th = copysignf(th, u);
  return 0.5f * v * (1.0f + th);
}

// ---- fused prep: weight transposes [0,6912) | LN1 [6912,7936) | mask pack [7936,7940)
__global__ __launch_bounds__(256) void prep_kernel(
    const float* __restrict__ w_qkv, const float* __restrict__ w_proj,
    const float* __restrict__ w_fc1, const float* __restrict__ w_fc2,
    unsigned short* __restrict__ tq, unsigned short* __restrict__ tp,
    unsigned short* __restrict__ t1, unsigned short* __restrict__ t2,
    const float* __restrict__ x, const float* __restrict__ g1,
    const float* __restrict__ b1, unsigned short* __restrict__ h_out,
    const int* __restrict__ am, unsigned long long* __restrict__ pm)
{
  __shared__ __align__(16) unsigned short tile[32][33];
  int id = blockIdx.x;
  if (id < 6912){
    const float* W; unsigned short* Wt; int K, N, tx_n;
    if (id < 1728)      { W = w_qkv;  Wt = tq; K = 768;  N = 2304; tx_n = 72; }
    else if (id < 2304) { W = w_proj; Wt = tp; K = 768;  N = 768;  tx_n = 24; id -= 1728; }
    else if (id < 4608) { W = w_fc1;  Wt = t1; K = 768;  N = 3072; tx_n = 96; id -= 2304; }
    else                { W = w_fc2;  Wt = t2; K = 3072; N = 768;  tx_n = 24; id -= 4608; }
    int n0 = (id % tx_n) * 32, k0 = (id / tx_n) * 32;
    int tx = threadIdx.x & 31, ty = threadIdx.x >> 5;
#pragma unroll
    for (int i = 0; i < 32; i += 8)
      tile[ty + i][tx] = f2bf(W[(size_t)(k0 + ty + i) * N + n0 + tx]);
    __syncthreads();
#pragma unroll
    for (int i = 0; i < 32; i += 8)
      Wt[(size_t)(n0 + ty + i) * K + k0 + tx] = tile[tx][ty + i];
  } else if (id < 7936){
    int row = (id - 6912) * 4 + (threadIdx.x >> 6);
    int lane = threadIdx.x & 63;
    const float* xr = x + (size_t)row * DIM;
    float4 v[3];
    float s = 0.f, s2 = 0.f;
#pragma unroll
    for (int j = 0; j < 3; ++j){
      v[j] = *(const float4*)(xr + j * 256 + lane * 4);
      s  += v[j].x + v[j].y + v[j].z + v[j].w;
      s2 += v[j].x*v[j].x + v[j].y*v[j].y + v[j].z*v[j].z + v[j].w*v[j].w;
    }
#pragma unroll
    for (int m = 1; m < 64; m <<= 1){ s += __shfl_xor(s, m, 64); s2 += __shfl_xor(s2, m, 64); }
    float mu  = s * (1.f / 768.f);
    float var = s2 * (1.f / 768.f) - mu * mu;
    float inv = rsqrtf(var + 1e-5f);
#pragma unroll
    for (int j = 0; j < 3; ++j){
      int c0 = j * 256 + lane * 4;
      float vv[4] = { v[j].x, v[j].y, v[j].z, v[j].w };
      ushort4 o4;
      o4.x = f2bf((vv[0] - mu) * inv * g1[c0 + 0] + b1[c0 + 0]);
      o4.y = f2bf((vv[1] - mu) * inv * g1[c0 + 1] + b1[c0 + 1]);
      o4.z = f2bf((vv[2] - mu) * inv * g1[c0 + 2] + b1[c0 + 2]);
      o4.w = f2bf((vv[3] - mu) * inv * g1[c0 + 3] + b1[c0 + 3]);
      *(ushort4*)(h_out + (size_t)row * DIM + c0) = o4;
    }
  } else {
    int b = id - 7936;
    int lane = threadIdx.x & 63, w = threadIdx.x >> 6;
    for (int k = w; k < 16; k += 4){
      unsigned long long m = __ballot(am[b * 1024 + k * 64 + lane] != 0);
      if (lane == 0) pm[b * 16 + k] = m;
    }
  }
}

// ---------------- LayerNorm (LN2): fp32 in -> bf16 out, 1 wave per 768-row ----------
__global__ __launch_bounds__(256) void ln_kernel(const float* __restrict__ x,
    const float* __restrict__ g, const float* __restrict__ b,
    unsigned short* __restrict__ out)
{
  int row = blockIdx.x * 4 + (threadIdx.x >> 6);
  int lane = threadIdx.x & 63;
  const float* xr = x + (size_t)row * DIM;
  float4 v[3];
  float s = 0.f, s2 = 0.f;
#pragma unroll
  for (int j = 0; j < 3; ++j){
    v[j] = *(const float4*)(xr + j * 256 + lane * 4);
    s  += v[j].x + v[j].y + v[j].z + v[j].w;
    s2 += v[j].x*v[j].x + v[j].y*v[j].y + v[j].z*v[j].z + v[j].w*v[j].w;
  }
#pragma unroll
  for (int m = 1; m < 64; m <<= 1){ s += __shfl_xor(s, m, 64); s2 += __shfl_xor(s2, m, 64); }
  float mu  = s * (1.f / 768.f);
  float var = s2 * (1.f / 768.f) - mu * mu;
  float inv = rsqrtf(var + 1e-5f);
#pragma unroll
  for (int j = 0; j < 3; ++j){
    int c0 = j * 256 + lane * 4;
    float vv[4] = { v[j].x, v[j].y, v[j].z, v[j].w };
    ushort4 o4;
    o4.x = f2bf((vv[0] - mu) * inv * g[c0 + 0] + b[c0 + 0]);
    o4.y = f2bf((vv[1] - mu) * inv * g[c0 + 1] + b[c0 + 1]);
    o4.z = f2bf((vv[2] - mu) * inv * g[c0 + 2] + b[c0 + 2]);
    o4.w = f2bf((vv[3] - mu) * inv * g[c0 + 3] + b[c0 + 3]);
    *(ushort4*)(out + (size_t)row * DIM + c0) = o4;
  }
}

// ------- QKV GEMM: 256 thr, BM=128 x BN=96, rotated 3-buffer, split epilogue --------
__global__ __launch_bounds__(256) void gemm_qkv_kernel(
    const unsigned short* __restrict__ A,   // [M][768] bf16
    const unsigned short* __restrict__ Bt,  // [2304][768] bf16
    const float* __restrict__ bias,         // [2304]
    unsigned short* __restrict__ q_out,
    unsigned short* __restrict__ k_out,
    unsigned short* __restrict__ v_out,
    int M, int N, int K)
{
  constexpr int BM = 128, BN = 96, BK = 32, DEPTH = 3;
  constexpr int MI = 4, NI = 3;              // wave tile 64x48, wave grid 2x2
  constexpr int SMEM_B = DEPTH * (BM + BN) * BK * 2;   // 43008 B
  __shared__ __align__(16) char smem[SMEM_B];
  auto As = (unsigned short(*)[BM * BK])smem;
  auto Bs = (unsigned short(*)[BN * BK])(smem + DEPTH * BM * BK * 2);
  const int t = threadIdx.x, lane = t & 63, wid = t >> 6;
  const int lo = lane & 15, hi = lane >> 4;
  const int wr = wid >> 1, wc = wid & 1;

  const int gx = gridDim.x;
  const int nwg = gx * gridDim.y;
  const int lin = blockIdx.y * gx + blockIdx.x;
  const int swz = (lin & 7) * (nwg >> 3) + (lin >> 3);
  const int bm = (swz / gx) * BM, bn = (swz % gx) * BN;

  const unsigned short *p0, *p1, *p2, *p3;
  int d3;
  {
    int c, rp, r, q;
    c = t;       rp = c >> 2; r = rp ^ ((rp >> 2) & 1); q = (c & 3) ^ (r & 3);
    p0 = A  + (size_t)(bm + r) * K + q * 8;
    c = 256 + t; rp = c >> 2; r = rp ^ ((rp >> 2) & 1); q = (c & 3) ^ (r & 3);
    p1 = A  + (size_t)(bm + r) * K + q * 8;
    c = t;       rp = c >> 2; r = rp ^ ((rp >> 2) & 1); q = (c & 3) ^ (r & 3);
    p2 = Bt + (size_t)(bn + r) * K + q * 8;
    int c2w = (t < 128) ? 256 + t : t - 128;           // benign duplicate for t>=128
    c = c2w;     rp = c >> 2; r = rp ^ ((rp >> 2) & 1); q = (c & 3) ^ (r & 3);
    p3 = Bt + (size_t)(bn + r) * K + q * 8;
    d3 = c2w * 8;
  }
  int ofsA[MI], ofsB[NI];
#pragma unroll
  for (int i = 0; i < MI; ++i) ofsA[i] = swz_read(wr * 64 + i * 16 + lo, hi);
#pragma unroll
  for (int j = 0; j < NI; ++j) ofsB[j] = swz_read(wc * 48 + j * 16 + lo, hi);

  f32x4 acc[MI][NI];
#pragma unroll
  for (int i = 0; i < MI; ++i)
#pragma unroll
    for (int j = 0; j < NI; ++j) acc[i][j] = (f32x4){0.f, 0.f, 0.f, 0.f};

  const int NIT = K / BK;                    // 24, % 3 == 0
  auto stagefull = [&](int buf) __attribute__((always_inline)) {
    gload_lds16(p0, &As[buf][t * 8]);
    gload_lds16(p1, &As[buf][(256 + t) * 8]);
    gload_lds16(p2, &Bs[buf][t * 8]);
    gload_lds16(p3, &Bs[buf][d3]);
    p0 += BK; p1 += BK; p2 += BK; p3 += BK;
  };
  auto kbody = [&](int it, int RB, int WB) __attribute__((always_inline)) {
    if (it < NIT - 1) wait_vmcnt<4>(); else wait_vmcnt<0>();
    __builtin_amdgcn_sched_barrier(0);
    __builtin_amdgcn_s_barrier();
    __builtin_amdgcn_sched_barrier(0);
    if (it + 2 < NIT) stagefull(WB);
    const char* as = (const char*)As[RB];
    const char* bs = (const char*)Bs[RB];
    bf16x8 af[MI], bfr[NI];
#pragma unroll
    for (int i = 0; i < MI; ++i) af[i]  = *(const bf16x8*)(as + ofsA[i]);
#pragma unroll
    for (int j = 0; j < NI; ++j) bfr[j] = *(const bf16x8*)(bs + ofsB[j]);
    __builtin_amdgcn_s_setprio(1);
#pragma unroll
    for (int i = 0; i < MI; ++i)
#pragma unroll
      for (int j = 0; j < NI; ++j)
        acc[i][j] = __builtin_amdgcn_mfma_f32_16x16x32_bf16(af[i], bfr[j], acc[i][j], 0, 0, 0);
    __builtin_amdgcn_s_setprio(0);
  };

  stagefull(0);
  stagefull(1);
  for (int it = 0; it < NIT; it += 3){
    kbody(it,     0, 2);
    kbody(it + 1, 1, 0);
    kbody(it + 2, 2, 1);
  }

  __syncthreads();   // staging reads done; smem reusable

  // ---- split epilogue. acc: col=lane&15, row=(lane>>4)*4+r ----
  const int part = bn / 768;                 // 0=Q 1=K 2=V (uniform; 768 % 96 == 0)
  const int cloc = bn % 768;
  const int bb = bm >> 10, n0b = bm & 1023;
  unsigned short* ET = (unsigned short*)smem;
  if (part < 2){
    constexpr int LDE = 104;                 // 128 x 104 bf16 = 26.6KB
#pragma unroll
    for (int i = 0; i < MI; ++i)
#pragma unroll
      for (int j = 0; j < NI; ++j){
        int col_l = wc * 48 + j * 16 + lo;
        float bcol = bias[bn + col_l];
#pragma unroll
        for (int r = 0; r < 4; ++r)
          ET[(wr * 64 + i * 16 + hi * 4 + r) * LDE + col_l] = f2bf(acc[i][j][r] + bcol);
      }
    __syncthreads();
    unsigned short* dst0 = (part == 0) ? q_out : k_out;
#pragma unroll
    for (int p = 0; p < 8; ++p){
      int row = p * 16 + (t >> 4), chunk = t & 15;
      if (chunk < 12){
        int col = cloc + chunk * 8, hh = col >> 6, d0 = col & 63;
        *(bf16x8*)&dst0[((size_t)(bb * 12 + hh)) * 65536 + (n0b + row) * 64 + d0] =
            *(const bf16x8*)&ET[row * LDE + chunk * 8];
      }
    }
  } else {
    constexpr int LDV = 136;                 // 96 x 136 bf16 = 26.1KB, col-major store
#pragma unroll
    for (int i = 0; i < MI; ++i)
#pragma unroll
      for (int j = 0; j < NI; ++j){
        int col_l = wc * 48 + j * 16 + lo;
        float bcol = bias[bn + col_l];
#pragma unroll
        for (int r = 0; r < 4; ++r)
          ET[col_l * LDV + wr * 64 + i * 16 + hi * 4 + r] = f2bf(acc[i][j][r] + bcol);
      }
    __syncthreads();
#pragma unroll
    for (int p = 0; p < 6; ++p){
      int colg = p * 16 + (t >> 4), chunk = t & 15;
      int col = cloc + colg, hh = col >> 6, d = col & 63;
      *(bf16x8*)&v_out[((size_t)(bb * 12 + hh)) * 65536 + (size_t)d * 1024 + n0b + chunk * 8] =
          *(const bf16x8*)&ET[colg * LDV + chunk * 8];
    }
  }
}

// ------- 256-thread MFMA GEMM (FC1): 128x128, rotated 3-buffer, hoisted addressing --
// EPI: 0 bias->bf16, 1 bias+GELU(tanh)->bf16.  Requires (K/32) % 3 == 0.
template<int EPI>
__global__ __launch_bounds__(256) void gemm_kernel(
    const unsigned short* __restrict__ A,   // [M][K] bf16
    const unsigned short* __restrict__ Bt,  // [N][K] bf16
    const float* __restrict__ bias,         // [N]
    unsigned short* __restrict__ C,         // [M][N] bf16
    int M, int N, int K)
{
  constexpr int BM = 128, BN = 128, BK = 32, WM = 64, WN = 64, DEPTH = 3;
  constexpr int MI = WM / 16, NI = WN / 16;  // 4, 4
  constexpr int SMEM_B = DEPTH * (BM + BN) * BK * 2;   // 48KB
  __shared__ __align__(16) char smem[SMEM_B];
  auto As = (unsigned short(*)[BM * BK])smem;
  auto Bs = (unsigned short(*)[BN * BK])(smem + DEPTH * BM * BK * 2);
  const int t = threadIdx.x, lane = t & 63, wid = t >> 6;
  const int lo = lane & 15, hi = lane >> 4;
  const int wr = wid >> 1, wc = wid & 1;

  const int gx = gridDim.x;
  const int nwg = gx * gridDim.y;
  const int lin = blockIdx.y * gx + blockIdx.x;
  const int swz = (lin & 7) * (nwg >> 3) + (lin >> 3);
  const int bm = (swz / gx) * BM, bn = (swz % gx) * BN;

  const unsigned short *a0, *a1, *b0, *b1;
  {
    int rp = t >> 2, r = rp ^ ((rp >> 2) & 1), q = (t & 3) ^ (r & 3);
    a0 = A  + (size_t)(bm + r) * K + q * 8;
    b0 = Bt + (size_t)(bn + r) * K + q * 8;
    int c = 256 + t;
    rp = c >> 2; r = rp ^ ((rp >> 2) & 1); q = (c & 3) ^ (r & 3);
    a1 = A  + (size_t)(bm + r) * K + q * 8;
    b1 = Bt + (size_t)(bn + r) * K + q * 8;
  }
  int ofsA[MI], ofsB[NI];
#pragma unroll
  for (int i = 0; i < MI; ++i) ofsA[i] = swz_read(wr * WM + i * 16 + lo, hi);
#pragma unroll
  for (int j = 0; j < NI; ++j) ofsB[j] = swz_read(wc * WN + j * 16 + lo, hi);

  f32x4 acc[MI][NI];
#pragma unroll
  for (int i = 0; i < MI; ++i)
#pragma unroll
    for (int j = 0; j < NI; ++j) acc[i][j] = (f32x4){0.f, 0.f, 0.f, 0.f};

  const int NIT = K / BK;                  // 24; % 3 == 0
  auto stagefull = [&](int buf) __attribute__((always_inline)) {
    gload_lds16(a0, &As[buf][t * 8]);
    gload_lds16(a1, &As[buf][(256 + t) * 8]);
    gload_lds16(b0, &Bs[buf][t * 8]);
    gload_lds16(b1, &Bs[buf][(256 + t) * 8]);
    a0 += BK; a1 += BK; b0 += BK; b1 += BK;
  };
  auto kbody = [&](int it, int RB, int WB) __attribute__((always_inline)) {
    if (it < NIT - 1) wait_vmcnt<4>(); else wait_vmcnt<0>();
    __builtin_amdgcn_sched_barrier(0);
    __builtin_amdgcn_s_barrier();
    __builtin_amdgcn_sched_barrier(0);
    if (it + 2 < NIT) stagefull(WB);
    const char* as = (const char*)As[RB];
    const char* bs = (const char*)Bs[RB];
    bf16x8 af[MI], bfr[NI];
#pragma unroll
    for (int i = 0; i < MI; ++i) af[i]  = *(const bf16x8*)(as + ofsA[i]);
#pragma unroll
    for (int j = 0; j < NI; ++j) bfr[j] = *(const bf16x8*)(bs + ofsB[j]);
    __builtin_amdgcn_s_setprio(1);
#pragma unroll
    for (int i = 0; i < MI; ++i)
#pragma unroll
      for (int j = 0; j < NI; ++j)
        acc[i][j] = __builtin_amdgcn_mfma_f32_16x16x32_bf16(af[i], bfr[j], acc[i][j], 0, 0, 0);
    __builtin_amdgcn_s_setprio(0);
  };

  stagefull(0);
  stagefull(1);
  for (int it = 0; it < NIT; it += 3){
    kbody(it,     0, 2);
    kbody(it + 1, 1, 0);
    kbody(it + 2, 2, 1);
  }

  __syncthreads();   // staging reads done; smem reusable for the epilogue

  constexpr int LDE = BN + 8;            // 136 bf16, 272 B row
  unsigned short* ET = (unsigned short*)smem;
#pragma unroll
  for (int i = 0; i < MI; ++i)
#pragma unroll
    for (int j = 0; j < NI; ++j){
      float bcol = bias[bn + wc * WN + j * 16 + lo];
#pragma unroll
      for (int r = 0; r < 4; ++r){
        float v = acc[i][j][r] + bcol;
        if constexpr (EPI == 1) v = gelu_fast(v);
        ET[(wr * WM + i * 16 + hi * 4 + r) * LDE + wc * WN + j * 16 + lo] = f2bf(v);
      }
    }
  __syncthreads();
#pragma unroll
  for (int p = 0; p < BM / 16; ++p){     // 16 lanes x 16B = 256B-contiguous row runs
    int row = p * 16 + (t >> 4), chunk = t & 15;
    *(bf16x8*)&C[(size_t)(bm + row) * N + bn + chunk * 8] =
        *(const bf16x8*)&ET[row * LDE + chunk * 8];
  }
}

// ------- N=768 GEMM (proj, FC2): K-split-in-block, 512 thr, BM=128 x BN=96 ----------
__global__ __launch_bounds__(512) void gemm_ks_kernel(
    const unsigned short* __restrict__ A,   // [M][K] bf16
    const unsigned short* __restrict__ Bt,  // [N][K] bf16
    const float* __restrict__ bias,         // [N]
    const float* __restrict__ resid,        // [M][N]
    float* __restrict__ C,                  // [M][N]
    int M, int N, int K)
{
  constexpr int BM = 128, BN = 96, BK = 64, DEPTH = 3;
  constexpr int MI = 4, NI = 3;
  constexpr int ACH = BM * BK / 8;         // 1024
  constexpr int BCH = BN * BK / 8;         // 768
  constexpr int NC = 4;
  constexpr int TILE_A = BM * BK * 2, TILE_B = BN * BK * 2;
  constexpr int LDE = BN + 4;              // 100 floats
  constexpr int SMEM_B = (DEPTH * (TILE_A + TILE_B) > BM * LDE * 4)
                       ?  DEPTH * (TILE_A + TILE_B) : BM * LDE * 4;   // 84KB
  __shared__ __align__(16) char smem[SMEM_B];
  auto As = (unsigned short(*)[BM * BK])smem;
  auto Bs = (unsigned short(*)[BN * BK])(smem + DEPTH * TILE_A);
  const int t = threadIdx.x, lane = t & 63, wid = t >> 6;
  const int lo = lane & 15, hi = lane >> 4;
  const int ks = wid & 1, wc = (wid >> 1) & 1, wr = wid >> 2;

  const int gx = gridDim.x;
  const int nwg = gx * gridDim.y;
  const int lin = blockIdx.y * gx + blockIdx.x;
  const int swz = (lin & 7) * (nwg >> 3) + (lin >> 3);
  const int bm = (swz / gx) * BM, bn = (swz % gx) * BN;

  auto stage = [&](int buf, int k0){
#pragma unroll
    for (int u = 0; u < NC; ++u){
      int c = u * 512 + t;
      if (c < ACH){
        int r = c >> 3, q = (c & 7) ^ (r & 7);
        gload_lds16(A + (size_t)(bm + r) * K + k0 + q * 8, &As[buf][c * 8]);
      } else {
        int c2 = c - ACH;
        if (c2 >= BCH) c2 -= BCH;
        int r = c2 >> 3, q = (c2 & 7) ^ (r & 7);
        gload_lds16(Bt + (size_t)(bn + r) * K + k0 + q * 8, &Bs[buf][c2 * 8]);
      }
    }
  };
  auto rd = [&](const char* base, int row, int q)->bf16x8 {
    return *(const bf16x8*)(base + row * 128 + ((q ^ (row & 7)) << 4));
  };

  f32x4 acc[MI][NI];
#pragma unroll
  for (int i = 0; i < MI; ++i)
#pragma unroll
    for (int j = 0; j < NI; ++j) acc[i][j] = (f32x4){0.f, 0.f, 0.f, 0.f};

  const int NIT = K / BK;                  // 12 (proj) / 48 (FC2)
  stage(0, 0);
  stage(1, BK);
  const int qk = ks * 4 + hi;
  for (int it = 0; it < NIT; ++it){
    if (it < NIT - 1) wait_vmcnt<NC>();
    else wait_vmcnt<0>();
    __builtin_amdgcn_sched_barrier(0);
    __builtin_amdgcn_s_barrier();
    __builtin_amdgcn_sched_barrier(0);
    if (it + 2 < NIT) stage((it + 2) % DEPTH, (it + 2) * BK);
    const char* as = (const char*)As[it % DEPTH];
    const char* bs = (const char*)Bs[it % DEPTH];
    bf16x8 af[MI], bfr[NI];
#pragma unroll
    for (int i = 0; i < MI; ++i)  af[i]  = rd(as, wr * 64 + i * 16 + lo, qk);
#pragma unroll
    for (int j = 0; j < NI; ++j) bfr[j] = rd(bs, wc * 48 + j * 16 + lo, qk);
    __builtin_amdgcn_s_setprio(1);
#pragma unroll
    for (int i = 0; i < MI; ++i)
#pragma unroll
      for (int j = 0; j < NI; ++j)
        acc[i][j] = __builtin_amdgcn_mfma_f32_16x16x32_bf16(af[i], bfr[j], acc[i][j], 0, 0, 0);
    __builtin_amdgcn_s_setprio(0);
  }

  // ---- ks reduction (+bias) in LDS ----
  __syncthreads();
  float* ET = (float*)smem;
  if (ks == 1){
#pragma unroll
    for (int i = 0; i < MI; ++i)
#pragma unroll
      for (int j = 0; j < NI; ++j)
#pragma unroll
        for (int r = 0; r < 4; ++r)
          ET[(wr * 64 + i * 16 + hi * 4 + r) * LDE + wc * 48 + j * 16 + lo] = acc[i][j][r];
  }
  __syncthreads();
  if (ks == 0){
#pragma unroll
    for (int i = 0; i < MI; ++i)
#pragma unroll
      for (int j = 0; j < NI; ++j){
        int col_l = wc * 48 + j * 16 + lo;
        float bcol = bias[bn + col_l];
#pragma unroll
        for (int r = 0; r < 4; ++r){
          int idx = (wr * 64 + i * 16 + hi * 4 + r) * LDE + col_l;
          ET[idx] = ET[idx] + acc[i][j][r] + bcol;
        }
      }
  }
  __syncthreads();
  {
    int row = t >> 2, q = t & 3;
    const float* rrow = resid + (size_t)(bm + row) * N + bn;
    float* crow = C + (size_t)(bm + row) * N + bn;
#pragma unroll
    for (int k = 0; k < 6; ++k){
      int c4 = (q + k * 4) * 4;
      float4 v = *(const float4*)&ET[row * LDE + c4];
      float4 rs = *(const float4*)&rrow[c4];
      v.x += rs.x; v.y += rs.y; v.z += rs.z; v.w += rs.w;
      *(float4*)&crow[c4] = v;
    }
  }
}

// ---- Flash attention: T14 async-stage + double-buffered K/V, 1 barrier per iter ----
__global__ __launch_bounds__(256) void attn_kernel(
    const unsigned short* __restrict__ Qs,   // [b*h][1024][64]
    const unsigned short* __restrict__ Ks,   // [b*h][1024][64]
    const unsigned short* __restrict__ Vts,  // [b*h][64][1024]  (V transposed)
    const unsigned long long* __restrict__ pm,
    unsigned short* __restrict__ o)          // [token][768]
{
  constexpr int LD = 72;
  __shared__ __align__(16) unsigned short Kl[2][64 * LD];
  __shared__ __align__(16) unsigned short Vt[2][64 * LD];
  __shared__ __align__(16) unsigned short Pl[4][16 * LD];
  const int qb = blockIdx.x, h = blockIdx.y, b = blockIdx.z;
  const int t = threadIdx.x, wid = t >> 6, lane = t & 63;
  const int lo = lane & 15, hi = lane >> 4;
  const size_t bh = (size_t)b * 12 + h;

  const unsigned short* Qg = Qs + (bh * 1024 + qb * 64 + wid * 16 + lo) * 64;
  bf16x8 qf0 = *(const bf16x8*)(Qg + hi * 8);
  bf16x8 qf1 = *(const bf16x8*)(Qg + 32 + hi * 8);

  f32x4 oacc[4];
#pragma unroll
  for (int dj = 0; dj < 4; ++dj) oacc[dj] = (f32x4){0.f, 0.f, 0.f, 0.f};
  float l_part = 0.f;

  const int srow = t >> 2, scol = (t & 3) * 16;
  const int sdst = srow * LD + scol;
  const unsigned short* kg = Ks  + bh * 65536 + srow * 64 + scol;
  const unsigned short* vg = Vts + bh * 65536 + srow * 1024 + scol;
  unsigned short* pw = &Pl[wid][0];

  bf16x8 kn0 = *(const bf16x8*)(kg);
  bf16x8 kn1 = *(const bf16x8*)(kg + 8);
  bf16x8 vn0 = *(const bf16x8*)(vg);
  bf16x8 vn1 = *(const bf16x8*)(vg + 8);
  *(bf16x8*)&Kl[0][sdst]     = kn0;
  *(bf16x8*)&Kl[0][sdst + 8] = kn1;
  *(bf16x8*)&Vt[0][sdst]     = vn0;
  *(bf16x8*)&Vt[0][sdst + 8] = vn1;
  __syncthreads();

  for (int kt = 0; kt < 16; ++kt){
    const int cur = kt & 1;
    if (kt + 1 < 16){
      kn0 = *(const bf16x8*)(kg + (kt + 1) * 4096);
      kn1 = *(const bf16x8*)(kg + (kt + 1) * 4096 + 8);
      vn0 = *(const bf16x8*)(vg + (kt + 1) * 64);
      vn1 = *(const bf16x8*)(vg + (kt + 1) * 64 + 8);
    }

    f32x4 s[4];
#pragma unroll
    for (int nj = 0; nj < 4; ++nj) s[nj] = (f32x4){0.f, 0.f, 0.f, 0.f};
    __builtin_amdgcn_s_setprio(1);
#pragma unroll
    for (int kk = 0; kk < 2; ++kk){
      bf16x8 q = kk ? qf1 : qf0;
#pragma unroll
      for (int nj = 0; nj < 4; ++nj){
        bf16x8 kf = *(const bf16x8*)&Kl[cur][(nj * 16 + lo) * LD + kk * 32 + hi * 8];
        s[nj] = __builtin_amdgcn_mfma_f32_16x16x32_bf16(kf, q, s[nj], 0, 0, 0);
      }
    }
    __builtin_amdgcn_s_setprio(0);

    unsigned long long w = pm[b * 16 + kt] >> (hi * 4);
#pragma unroll
    for (int nj = 0; nj < 4; ++nj){
      float p[4];
#pragma unroll
      for (int r = 0; r < 4; ++r){
        float e = __expf(fmaf(s[nj][r], 0.125f, -16.0f));
        e = ((unsigned)(w >> (nj * 16 + r)) & 1u) ? e : 0.0f;
        l_part += e;
        p[r] = e;
      }
      unsigned w0 = cvt_pk_bf16(p[0], p[1]);
      unsigned w1 = cvt_pk_bf16(p[2], p[3]);
      *(uint2*)&pw[lo * LD + nj * 16 + hi * 4] = make_uint2(w0, w1);
    }
    asm volatile("" ::: "memory");
    bf16x8 pf0 = *(const bf16x8*)&pw[lo * LD + hi * 8];
    bf16x8 pf1 = *(const bf16x8*)&pw[lo * LD + 32 + hi * 8];
    __builtin_amdgcn_s_setprio(1);
#pragma unroll
    for (int kk = 0; kk < 2; ++kk){
      bf16x8 pf = kk ? pf1 : pf0;
#pragma unroll
      for (int dj = 0; dj < 4; ++dj){
        bf16x8 vf = *(const bf16x8*)&Vt[cur][(dj * 16 + lo) * LD + kk * 32 + hi * 8];
        oacc[dj] = __builtin_amdgcn_mfma_f32_16x16x32_bf16(vf, pf, oacc[dj], 0, 0, 0);
      }
    }
    __builtin_amdgcn_s_setprio(0);

    if (kt + 1 < 16){
      *(bf16x8*)&Kl[cur ^ 1][sdst]     = kn0;
      *(bf16x8*)&Kl[cur ^ 1][sdst + 8] = kn1;
      *(bf16x8*)&Vt[cur ^ 1][sdst]     = vn0;
      *(bf16x8*)&Vt[cur ^ 1][sdst + 8] = vn1;
    }
    __syncthreads();
  }

  float l = l_part;
  l += __shfl_xor(l, 16, 64);
  l += __shfl_xor(l, 32, 64);
  float inv = 1.0f / l;
  size_t orow = (size_t)b * 1024 + qb * 64 + wid * 16 + lo;
#pragma unroll
  for (int dj = 0; dj < 4; ++dj){
    unsigned w0 = (unsigned)f2bf(oacc[dj][0] * inv) | ((unsigned)f2bf(oacc[dj][1] * inv) << 16);
    unsigned w1 = (unsigned)f2bf(oacc[dj][2] * inv) | ((unsigned)f2bf(oacc[dj][3] * inv) << 16);
    *(uint2*)&o[orow * DIM + h * 64 + dj * 16 + hi * 4] = make_uint2(w0, w1);
  }
}

extern "C" void kernel_launch(void* const* d_in, const int* in_sizes, int n_in,
                              void* d_out, int out_size, void* d_ws, size_t ws_size,
                              hipStream_t stream)
{
  const float* x      = (const float*)d_in[0];
  const int*   amask  = (const int*)  d_in[1];
  const float* ln1_g  = (const float*)d_in[2];
  const float* ln1_b  = (const float*)d_in[3];
  const float* ln2_g  = (const float*)d_in[4];
  const float* ln2_b  = (const float*)d_in[5];
  const float* w_qkv  = (const float*)d_in[6];
  const float* b_qkv  = (const float*)d_in[7];
  const float* w_proj = (const float*)d_in[8];
  const float* b_proj = (const float*)d_in[9];
  const float* w_fc1  = (const float*)d_in[10];
  const float* b_fc1  = (const float*)d_in[11];
  const float* w_fc2  = (const float*)d_in[12];
  const float* b_fc2  = (const float*)d_in[13];
  float* outp = (float*)d_out;

  char* w = (char*)d_ws;
  auto alloc = [&](size_t bytes){ char* p = w; w += (bytes + 255) & ~(size_t)255; return p; };

  char* p0 = alloc((size_t)4 * 6291456);
  unsigned short* Qs   = (unsigned short*)p0;
  unsigned short* Ks   = (unsigned short*)(p0 + 6291456);
  unsigned short* Vts  = (unsigned short*)(p0 + 2 * 6291456);
  unsigned short* o_bf = (unsigned short*)(p0 + 3 * 6291456);
  unsigned short* a1   = (unsigned short*)p0;
  unsigned short* h_bf = (unsigned short*)alloc((size_t)NTOK * DIM * 2);
  unsigned short* h2   = h_bf;
  float*          x1   = (float*)alloc((size_t)NTOK * DIM * 4);
  unsigned short* wqkvT = (unsigned short*)alloc((size_t)3 * DIM * DIM * 2);
  unsigned short* wprojT= (unsigned short*)alloc((size_t)DIM * DIM * 2);
  unsigned short* wfc1T = (unsigned short*)alloc((size_t)HID * DIM * 2);
  unsigned short* wfc2T = (unsigned short*)alloc((size_t)DIM * HID * 2);
  unsigned long long* pmask = (unsigned long long*)alloc(4 * 16 * 8);

  // fused: 4 weight transposes + LN1 + mask pack
  prep_kernel<<<7940, 256, 0, stream>>>(w_qkv, w_proj, w_fc1, w_fc2,
                                        wqkvT, wprojT, wfc1T, wfc2T,
                                        x, ln1_g, ln1_b, h_bf, amask, pmask);

  gemm_qkv_kernel<<<dim3(2304 / 96, NTOK / 128), 256, 0, stream>>>(
      h_bf, wqkvT, b_qkv, Qs, Ks, Vts, NTOK, 2304, DIM);
  attn_kernel<<<dim3(16, 12, 4), 256, 0, stream>>>(Qs, Ks, Vts, pmask, o_bf);
  gemm_ks_kernel<<<dim3(DIM / 96, NTOK / 128), 512, 0, stream>>>(
      o_bf, wprojT, b_proj, x, x1, NTOK, DIM, DIM);
  ln_kernel<<<NTOK / 4, 256, 0, stream>>>(x1, ln2_g, ln2_b, h2);
  gemm_kernel<1><<<dim3(HID / 128, NTOK / 128), 256, 0, stream>>>(
      h2, wfc1T, b_fc1, a1, NTOK, HID, DIM);
  gemm_ks_kernel<<<dim3(DIM / 96, NTOK / 128), 512, 0, stream>>>(
      a1, wfc2T, b_fc2, x1, outp, NTOK, DIM, HID);
}